// Round 8
// baseline (381.411 us; speedup 1.0000x reference)
//
#include <hip/hip_runtime.h>
#include <math.h>

#define Bn 32
#define Pn 42840
#define On 64
#define NIn 8
#define Cn 11
#define ATT_N (32*56*96)
#define THRESHOLD_F 0.4f
#define THETA_F 0.1f
#define CHn 16
#define CHUNK ((Pn + CHn - 1)/CHn)

// IoU of two corner-format boxes, mirroring the jnp op order exactly.
__device__ __forceinline__ float iou_c(float ax1,float ay1,float ax2,float ay2,
                                       float bx1,float by1,float bx2,float by2){
  float ltx=fmaxf(ax1,bx1), lty=fmaxf(ay1,by1);
  float rbx=fminf(ax2,bx2), rby=fminf(ay2,by2);
  float w=fmaxf(rbx-ltx,0.0f), h=fmaxf(rby-lty,0.0f);
  float inter=w*h;
  float aa=(ax2-ax1)*(ay2-ay1);
  float ab=(bx2-bx1)*(by2-by1);
  return inter/((aa+ab)-inter);
}

// ---- seg loss: sum of max(log1p(-a), -100); negated at the end ----
__global__ void seg_kernel(const float* __restrict__ att, double* __restrict__ acc){
  int i = blockIdx.x*256 + threadIdx.x;
  float v = 0.0f;
  if (i < ATT_N) v = fmaxf(log1pf(-att[i]), -100.0f);
  __shared__ float s[256];
  int t = threadIdx.x;
  s[t]=v; __syncthreads();
  for (int st=128; st>0; st>>=1){ if (t<st) s[t]+=s[t+st]; __syncthreads(); }
  if (t==0) atomicAdd(&acc[0], (double)s[0]);
}

// ---- phase A: per (b,p): max/argmax over objects (first occurrence), ignored flag ----
__global__ void phaseA_kernel(const float* __restrict__ boxes,
                              const float* __restrict__ ign,
                              const float* __restrict__ priors,
                              float* __restrict__ ov_prior,
                              int* __restrict__ objinfo){
  __shared__ float sb[On*4];
  __shared__ float si[NIn*4];
  int b = blockIdx.y;
  int t = threadIdx.x;
  if (t < On*4)  sb[t] = boxes[(size_t)b*On*4 + t];
  if (t < NIn*4) si[t] = ign[(size_t)b*NIn*4 + t];
  __syncthreads();
  int p = blockIdx.x*256 + t;
  if (p >= Pn) return;
  float4 pc = ((const float4*)priors)[p];
  float px1 = pc.x - pc.z/2.0f, py1 = pc.y - pc.w/2.0f;
  float px2 = pc.x + pc.z/2.0f, py2 = pc.y + pc.w/2.0f;
  float best = -1.0f; int besto = 0;
  #pragma unroll 4
  for (int o=0;o<On;o++){
    float v = iou_c(sb[4*o],sb[4*o+1],sb[4*o+2],sb[4*o+3], px1,py1,px2,py2);
    if (v > best){ best = v; besto = o; }   // strict > keeps first argmax
  }
  float ig = iou_c(si[0],si[1],si[2],si[3], px1,py1,px2,py2);
  #pragma unroll
  for (int o=1;o<NIn;o++)
    ig = fmaxf(ig, iou_c(si[4*o],si[4*o+1],si[4*o+2],si[4*o+3], px1,py1,px2,py2));
  size_t bp = (size_t)b*Pn + p;
  ov_prior[bp] = best;
  objinfo[bp]  = besto | ((ig >= THETA_F) ? 256 : 0);
}

// ---- phase B: per (b,o): max/argmax over P (first occurrence via packed key) ----
__global__ void phaseB_kernel(const float* __restrict__ boxes,
                              const float* __restrict__ priors,
                              float* __restrict__ ov_obj,
                              int* __restrict__ prior_obj){
  int b = blockIdx.y, o = blockIdx.x, t = threadIdx.x;
  const float* bx = boxes + ((size_t)b*On + o)*4;
  float ax1=bx[0], ay1=bx[1], ax2=bx[2], ay2=bx[3];
  unsigned long long key = 0ull;   // loses to any real key (low32=~p > 0)
  for (int p=t; p<Pn; p+=256){
    float4 pc = ((const float4*)priors)[p];
    float px1 = pc.x - pc.z/2.0f, py1 = pc.y - pc.w/2.0f;
    float px2 = pc.x + pc.z/2.0f, py2 = pc.y + pc.w/2.0f;
    float v = iou_c(ax1,ay1,ax2,ay2, px1,py1,px2,py2);  // v >= 0 -> bits ordered
    unsigned long long k = ((unsigned long long)__float_as_uint(v) << 32)
                         | (unsigned long long)(0xFFFFFFFFu - (unsigned)p);
    if (k > key) key = k;
  }
  __shared__ unsigned long long sk[256];
  sk[t] = key; __syncthreads();
  for (int st=128; st>0; st>>=1){
    if (t<st && sk[t+st] > sk[t]) sk[t] = sk[t+st];
    __syncthreads();
  }
  if (t==0){
    ov_obj[(size_t)b*On+o]   = __uint_as_float((unsigned)(sk[0] >> 32));
    prior_obj[(size_t)b*On+o]= (int)(0xFFFFFFFFu - (unsigned)(sk[0] & 0xFFFFFFFFu));
  }
}

// ---- phase C: sequential per-batch scatter (set 1.0; last-write-wins rank) ----
__global__ void phaseC_kernel(const float* __restrict__ ov_obj,
                              const int* __restrict__ prior_obj,
                              float* __restrict__ ov_prior,
                              int* __restrict__ objinfo){
  int b = threadIdx.x;
  if (b >= Bn) return;
  int rank = -1;
  for (int o=0;o<On;o++){
    if (ov_obj[(size_t)b*On+o] > 0.0f){
      rank++;                                   // jranks = cumsum(valid)-1
      int p = prior_obj[(size_t)b*On+o];
      size_t bp = (size_t)b*Pn + p;
      ov_prior[bp] = 1.0f;
      objinfo[bp] = (objinfo[bp] & 256) | rank; // ascending o => overwrite == max(jr)
    }
  }
}

// ---- phase D: labels, CE, DIoU over positives, conf_neg array, partial sums ----
// Scores for a block's 256 priors are a CONTIGUOUS 256*11-float slab ->
// LDS-stage with coalesced float4 loads; per-thread reads at odd stride 11
// (2 lanes/bank = free). Breaks the objinfo->label->sc[label] global chain
// down to an LDS read.
__global__ void phaseD_kernel(const float* __restrict__ odm_locs,
                              const float* __restrict__ odm_scores,
                              const float* __restrict__ boxes,
                              const int* __restrict__ labels,
                              const float* __restrict__ priors,
                              const float* __restrict__ ov_prior,
                              const int* __restrict__ objinfo,
                              float* __restrict__ conf_neg,
                              int* __restrict__ n_pos,
                              double* __restrict__ acc){
  int b = blockIdx.y;
  int t = threadIdx.x;
  int pbase = blockIdx.x*256;
  int cnt = min(256, Pn - pbase);          // always a multiple of 4 (Pn%4==0)
  __shared__ float s_sc[256*Cn];           // 11264 B
  // cooperative coalesced stage: (b*Pn + pbase)*11 floats, 16B-aligned
  {
    const float4* src = (const float4*)(odm_scores + ((size_t)b*Pn + pbase)*Cn);
    float4* dst = (float4*)s_sc;
    int nf4 = (cnt*Cn) >> 2;
    for (int i=t; i<nf4; i+=256) dst[i] = src[i];
  }
  int p = pbase + t;
  // issue independent global loads before the barrier
  int info = 0; float ovp = 0.0f;
  size_t bp = (size_t)b*Pn + p;
  if (p < Pn){ info = objinfo[bp]; ovp = ov_prior[bp]; }
  __syncthreads();
  float locv = 0.0f, confpv = 0.0f; int posv = 0;
  if (p < Pn){
    int obj = info & 0xFF;
    bool ignored = (info & 256) != 0;
    int label = labels[b*On + obj];
    if (ovp < THRESHOLD_F) label = 0;
    bool pos = label > 0;
    const float* sc = s_sc + t*Cn;
    float m = sc[0];
    #pragma unroll
    for (int c=1;c<Cn;c++) m = fmaxf(m, sc[c]);
    float se = 0.0f;
    #pragma unroll
    for (int c=0;c<Cn;c++) se += expf(sc[c]-m);
    float conf = logf(se) - (sc[label]-m);
    conf_neg[bp] = (pos || ignored) ? 0.0f : conf;
    if (pos){
      posv = 1; confpv = conf;
      float4 pc = ((const float4*)priors)[p];
      float4 g  = ((const float4*)odm_locs)[bp];
      float cx = g.x*pc.z/10.0f + pc.x;
      float cy = g.y*pc.w/10.0f + pc.y;
      float w  = expf(g.z/5.0f)*pc.z;
      float h  = expf(g.w/5.0f)*pc.w;
      float dx1 = cx - w/2.0f, dy1 = cy - h/2.0f;
      float dx2 = cx + w/2.0f, dy2 = cy + h/2.0f;
      const float* gt = boxes + ((size_t)b*On + obj)*4;
      float gx1=gt[0], gy1=gt[1], gx2=gt[2], gy2=gt[3];
      float ltx=fmaxf(dx1,gx1), lty=fmaxf(dy1,gy1);
      float rbx=fminf(dx2,gx2), rby=fminf(dy2,gy2);
      float iw=fmaxf(rbx-ltx,0.0f), ih=fmaxf(rby-lty,0.0f);
      float inter=iw*ih;
      float ap=(dx2-dx1)*(dy2-dy1);
      float ag=(gx2-gx1)*(gy2-gy1);
      float iou = inter/((ap+ag)-inter);
      float cpx=(dx1+dx2)/2.0f, cpy=(dy1+dy2)/2.0f;
      float cgx=(gx1+gx2)/2.0f, cgy=(gy1+gy2)/2.0f;
      float ddx=cpx-cgx, ddy=cpy-cgy;
      float inter_diag = ddx*ddx + ddy*ddy;
      float cltx=fminf(dx1,gx1), clty=fminf(dy1,gy1);
      float crbx=fmaxf(dx2,gx2), crby=fmaxf(dy2,gy2);
      float odx=crbx-cltx, ody=crby-clty;
      float outer_diag = odx*odx + ody*ody;
      float diou = fminf(fmaxf(iou - inter_diag/outer_diag, -1.0f), 1.0f);
      locv = 1.0f - diou;
    }
  }
  __shared__ float sl[256]; __shared__ float scf[256]; __shared__ int sp[256];
  sl[t]=locv; scf[t]=confpv; sp[t]=posv;
  __syncthreads();
  for (int st=128; st>0; st>>=1){
    if (t<st){ sl[t]+=sl[t+st]; scf[t]+=scf[t+st]; sp[t]+=sp[t+st]; }
    __syncthreads();
  }
  if (t==0){
    if (sl[0]  != 0.0f) atomicAdd(&acc[1], (double)sl[0]);
    if (scf[0] != 0.0f) atomicAdd(&acc[2], (double)scf[0]);
    if (sp[0]  != 0)    atomicAdd(&n_pos[b], sp[0]);
  }
}

// ---- phase E (parallel radix-select, 3 rounds of 12/12/8 bits) ----
template<int ROUND>
__global__ void histE_kernel(const float* __restrict__ conf_neg,
                             const int* __restrict__ n_pos,
                             const unsigned* __restrict__ prefix,
                             unsigned* __restrict__ hist){
  int b = blockIdx.y, c = blockIdx.x, t = threadIdx.x;
  if (n_pos[b] <= 0) return;
  const int nb = (ROUND==2)?256:4096;
  __shared__ unsigned h[4096];
  for (int i=t;i<nb;i+=256) h[i]=0u;
  __syncthreads();
  unsigned pref = (ROUND==0)?0u:prefix[b];
  const float* cn = conf_neg + (size_t)b*Pn;
  int p0 = c*CHUNK, p1 = min(Pn, p0+CHUNK);
  for (int p=p0+t; p<p1; p+=256){
    unsigned key = __float_as_uint(cn[p]);
    if (ROUND==0){
      atomicAdd(&h[key>>20],1u);
    } else if (ROUND==1){
      if ((key>>20)==(pref>>20)) atomicAdd(&h[(key>>8)&0xFFFu],1u);
    } else {
      if ((key>>8)==(pref>>8)) atomicAdd(&h[key&0xFFu],1u);
    }
  }
  __syncthreads();
  unsigned* gh = hist + (size_t)b*4096;
  for (int i=t;i<nb;i+=256) if (h[i]) atomicAdd(&gh[i], h[i]);
}

template<int ROUND>
__global__ void scanE_kernel(const unsigned* __restrict__ hist,
                             const int* __restrict__ n_pos,
                             unsigned* __restrict__ prefix,
                             int* __restrict__ krem_st){
  int b = blockIdx.x, t = threadIdx.x;
  int K = 2*n_pos[b];
  if (K <= 0) return;
  const int nb = (ROUND==2)?256:4096;
  const int per = nb/256;
  const unsigned* gh = hist + (size_t)b*4096;
  unsigned cnt[per>0?per:1];
  unsigned ts = 0;
  #pragma unroll
  for (int i=0;i<per;i++){ cnt[i]=gh[t*per+i]; ts+=cnt[i]; }
  __shared__ unsigned sh[256];
  sh[t]=ts;
  __syncthreads();
  for (int off=1; off<256; off<<=1){
    unsigned v = (t+off<256)? sh[t+off]:0u;   // read (after barrier)
    __syncthreads();
    sh[t]+=v;                                  // write
    __syncthreads();
  }
  int krem = (ROUND==0)? K : krem_st[b];
  unsigned incl = sh[t];           // count of keys in bins >= this thread's lowest
  unsigned above = incl - ts;      // count in strictly-higher threads' bins
  if ((int)above < krem && krem <= (int)incl){
    int acc = (int)above;
    #pragma unroll
    for (int i=per-1;i>=0;i--){
      acc += (int)cnt[i];
      if (acc >= krem){
        unsigned sel = (unsigned)(t*per+i);
        int krem_new = krem - (acc - (int)cnt[i]);
        if (ROUND==0)      prefix[b]  = sel<<20;
        else if (ROUND==1) prefix[b] |= sel<<8;
        else               prefix[b] |= sel;
        krem_st[b]=krem_new;
        break;
      }
    }
  }
}

// Final: sum = sum(v > t) + krem * t  (exact "first K of descending sort")
__global__ void finalE_kernel(const float* __restrict__ conf_neg,
                              const int* __restrict__ n_pos,
                              const unsigned* __restrict__ prefix,
                              const int* __restrict__ krem_st,
                              double* __restrict__ acc){
  int b = blockIdx.y, c = blockIdx.x, t = threadIdx.x;
  int K = 2*n_pos[b];
  if (K <= 0) return;
  const float* cn = conf_neg + (size_t)b*Pn;
  int p0=c*CHUNK, p1=min(Pn,p0+CHUNK);
  float s=0.0f;
  if (K >= Pn){
    for (int p=p0+t;p<p1;p+=256) s += cn[p];
  } else {
    unsigned tb = prefix[b];
    for (int p=p0+t;p<p1;p+=256){
      float v = cn[p];
      if (__float_as_uint(v) > tb) s += v;
    }
  }
  __shared__ float sr[256];
  sr[t]=s; __syncthreads();
  for (int st=128;st>0;st>>=1){ if(t<st) sr[t]+=sr[t+st]; __syncthreads(); }
  if (t==0){
    double add = (double)sr[0];
    if (c==0 && K < Pn) add += (double)krem_st[b] * (double)__uint_as_float(prefix[b]);
    if (add != 0.0) atomicAdd(&acc[3], add);
  }
}

// ---- final combine ----
__global__ void final_kernel(const int* __restrict__ n_pos,
                             const double* __restrict__ acc,
                             float* __restrict__ out){
  if (threadIdx.x==0 && blockIdx.x==0){
    int tp = 0;
    for (int b=0;b<Bn;b++) tp += n_pos[b];
    float total = (float)tp;
    float conf_loss = (float)(acc[3] + acc[2]) / total;
    float loc_loss  = (float)acc[1] / total;
    float seg_loss  = -(float)acc[0];
    out[0] = conf_loss + loc_loss + seg_loss;
  }
}

extern "C" void kernel_launch(void* const* d_in, const int* in_sizes, int n_in,
                              void* d_out, int out_size, void* d_ws, size_t ws_size,
                              hipStream_t stream) {
  const float* odm_locs   = (const float*)d_in[0];
  const float* odm_scores = (const float*)d_in[1];
  const float* att        = (const float*)d_in[2];
  const float* boxes      = (const float*)d_in[3];
  const int*   labels     = (const int*)d_in[4];
  const float* ign        = (const float*)d_in[5];
  const float* priors     = (const float*)d_in[6];
  float* out = (float*)d_out;

  size_t np = (size_t)Bn * Pn;
  float* ov_prior  = (float*)d_ws;                 // B*P f32
  int*   objinfo   = (int*)(ov_prior + np);        // B*P i32 (bits0-7 obj, bit8 ignored)
  float* conf_neg  = (float*)(objinfo + np);       // B*P f32
  float* ov_obj    = conf_neg + np;                // B*O f32
  int*   prior_obj = (int*)(ov_obj + (size_t)Bn*On); // B*O i32
  int*   n_pos     = prior_obj + (size_t)Bn*On;    // B i32
  double* acc      = (double*)(n_pos + Bn);        // [seg, loc, conf_pos, conf_hard]

  // radix-select scratch lives in the ov_prior region (dead after phaseD):
  // 3 x Bn x 4096 u32 hists + Bn prefix + Bn krem  (1.5 MB < 5.4 MB)
  unsigned* histB  = (unsigned*)ov_prior;
  unsigned* prefix = histB + 3*(size_t)Bn*4096;
  int*      krem   = (int*)(prefix + Bn);

  // zero only the accumulators (all big arrays are fully rewritten each call)
  hipMemsetAsync(n_pos, 0, Bn*sizeof(int) + 4*sizeof(double), stream);

  int pblocks = (Pn + 255) / 256;
  seg_kernel  <<<(ATT_N+255)/256, 256, 0, stream>>>(att, acc);
  phaseA_kernel<<<dim3(pblocks, Bn), 256, 0, stream>>>(boxes, ign, priors, ov_prior, objinfo);
  phaseB_kernel<<<dim3(On, Bn),      256, 0, stream>>>(boxes, priors, ov_obj, prior_obj);
  phaseC_kernel<<<1, 64, 0, stream>>>(ov_obj, prior_obj, ov_prior, objinfo);
  phaseD_kernel<<<dim3(pblocks, Bn), 256, 0, stream>>>(odm_locs, odm_scores, boxes, labels,
                                                       priors, ov_prior, objinfo,
                                                       conf_neg, n_pos, acc);
  // ov_prior is dead from here; reuse as radix scratch.
  hipMemsetAsync(histB, 0, 3*(size_t)Bn*4096*sizeof(unsigned), stream);
  histE_kernel<0><<<dim3(CHn, Bn), 256, 0, stream>>>(conf_neg, n_pos, prefix, histB);
  scanE_kernel<0><<<Bn, 256, 0, stream>>>(histB, n_pos, prefix, krem);
  histE_kernel<1><<<dim3(CHn, Bn), 256, 0, stream>>>(conf_neg, n_pos, prefix, histB + (size_t)Bn*4096);
  scanE_kernel<1><<<Bn, 256, 0, stream>>>(histB + (size_t)Bn*4096, n_pos, prefix, krem);
  histE_kernel<2><<<dim3(CHn, Bn), 256, 0, stream>>>(conf_neg, n_pos, prefix, histB + 2*(size_t)Bn*4096);
  scanE_kernel<2><<<Bn, 256, 0, stream>>>(histB + 2*(size_t)Bn*4096, n_pos, prefix, krem);
  finalE_kernel<<<dim3(CHn, Bn), 256, 0, stream>>>(conf_neg, n_pos, prefix, krem, acc);
  final_kernel<<<1, 64, 0, stream>>>(n_pos, acc, out);
}

// Round 9
// 297.755 us; speedup vs baseline: 1.2810x; 1.2810x over previous
//
#include <hip/hip_runtime.h>
#include <math.h>

#define Bn 32
#define Pn 42840
#define On 64
#define NIn 8
#define Cn 11
#define ATT_N (32*56*96)
#define THRESHOLD_F 0.4f
#define THETA_F 0.1f
#define CHn 16
#define CHUNK ((Pn + CHn - 1)/CHn)

// IoU of two corner-format boxes, mirroring the jnp op order exactly.
__device__ __forceinline__ float iou_c(float ax1,float ay1,float ax2,float ay2,
                                       float bx1,float by1,float bx2,float by2){
  float ltx=fmaxf(ax1,bx1), lty=fmaxf(ay1,by1);
  float rbx=fminf(ax2,bx2), rby=fminf(ay2,by2);
  float w=fmaxf(rbx-ltx,0.0f), h=fmaxf(rby-lty,0.0f);
  float inter=w*h;
  float aa=(ax2-ax1)*(ay2-ay1);
  float ab=(bx2-bx1)*(by2-by1);
  return inter/((aa+ab)-inter);
}

// ---- seg loss: sum of max(log1p(-a), -100); negated at the end ----
__global__ void seg_kernel(const float* __restrict__ att, double* __restrict__ acc){
  int i = blockIdx.x*256 + threadIdx.x;
  float v = 0.0f;
  if (i < ATT_N) v = fmaxf(log1pf(-att[i]), -100.0f);
  __shared__ float s[256];
  int t = threadIdx.x;
  s[t]=v; __syncthreads();
  for (int st=128; st>0; st>>=1){ if (t<st) s[t]+=s[t+st]; __syncthreads(); }
  if (t==0) atomicAdd(&acc[0], (double)s[0]);
}

// ---- phase A: per (b,p): max/argmax over objects (first occurrence), ignored flag ----
__global__ void phaseA_kernel(const float* __restrict__ boxes,
                              const float* __restrict__ ign,
                              const float* __restrict__ priors,
                              float* __restrict__ ov_prior,
                              int* __restrict__ objinfo){
  __shared__ float sb[On*4];
  __shared__ float si[NIn*4];
  int b = blockIdx.y;
  int t = threadIdx.x;
  if (t < On*4)  sb[t] = boxes[(size_t)b*On*4 + t];
  if (t < NIn*4) si[t] = ign[(size_t)b*NIn*4 + t];
  __syncthreads();
  int p = blockIdx.x*256 + t;
  if (p >= Pn) return;
  float4 pc = ((const float4*)priors)[p];
  float px1 = pc.x - pc.z/2.0f, py1 = pc.y - pc.w/2.0f;
  float px2 = pc.x + pc.z/2.0f, py2 = pc.y + pc.w/2.0f;
  float best = -1.0f; int besto = 0;
  #pragma unroll 4
  for (int o=0;o<On;o++){
    float v = iou_c(sb[4*o],sb[4*o+1],sb[4*o+2],sb[4*o+3], px1,py1,px2,py2);
    if (v > best){ best = v; besto = o; }   // strict > keeps first argmax
  }
  float ig = iou_c(si[0],si[1],si[2],si[3], px1,py1,px2,py2);
  #pragma unroll
  for (int o=1;o<NIn;o++)
    ig = fmaxf(ig, iou_c(si[4*o],si[4*o+1],si[4*o+2],si[4*o+3], px1,py1,px2,py2));
  size_t bp = (size_t)b*Pn + p;
  ov_prior[bp] = best;
  objinfo[bp]  = besto | ((ig >= THETA_F) ? 256 : 0);
}

// ---- phase B: per (b,o): max/argmax over P (first occurrence via packed key) ----
__global__ void phaseB_kernel(const float* __restrict__ boxes,
                              const float* __restrict__ priors,
                              float* __restrict__ ov_obj,
                              int* __restrict__ prior_obj){
  int b = blockIdx.y, o = blockIdx.x, t = threadIdx.x;
  const float* bx = boxes + ((size_t)b*On + o)*4;
  float ax1=bx[0], ay1=bx[1], ax2=bx[2], ay2=bx[3];
  unsigned long long key = 0ull;   // loses to any real key (low32=~p > 0)
  for (int p=t; p<Pn; p+=256){
    float4 pc = ((const float4*)priors)[p];
    float px1 = pc.x - pc.z/2.0f, py1 = pc.y - pc.w/2.0f;
    float px2 = pc.x + pc.z/2.0f, py2 = pc.y + pc.w/2.0f;
    float v = iou_c(ax1,ay1,ax2,ay2, px1,py1,px2,py2);  // v >= 0 -> bits ordered
    unsigned long long k = ((unsigned long long)__float_as_uint(v) << 32)
                         | (unsigned long long)(0xFFFFFFFFu - (unsigned)p);
    if (k > key) key = k;
  }
  __shared__ unsigned long long sk[256];
  sk[t] = key; __syncthreads();
  for (int st=128; st>0; st>>=1){
    if (t<st && sk[t+st] > sk[t]) sk[t] = sk[t+st];
    __syncthreads();
  }
  if (t==0){
    ov_obj[(size_t)b*On+o]   = __uint_as_float((unsigned)(sk[0] >> 32));
    prior_obj[(size_t)b*On+o]= (int)(0xFFFFFFFFu - (unsigned)(sk[0] & 0xFFFFFFFFu));
  }
}

// ---- phase C: sequential per-batch scatter (set 1.0; last-write-wins rank) ----
__global__ void phaseC_kernel(const float* __restrict__ ov_obj,
                              const int* __restrict__ prior_obj,
                              float* __restrict__ ov_prior,
                              int* __restrict__ objinfo){
  int b = threadIdx.x;
  if (b >= Bn) return;
  int rank = -1;
  for (int o=0;o<On;o++){
    if (ov_obj[(size_t)b*On+o] > 0.0f){
      rank++;                                   // jranks = cumsum(valid)-1
      int p = prior_obj[(size_t)b*On+o];
      size_t bp = (size_t)b*Pn + p;
      ov_prior[bp] = 1.0f;
      objinfo[bp] = (objinfo[bp] & 256) | rank; // ascending o => overwrite == max(jr)
    }
  }
}

// ---- phase D: 4 priors/thread, direct loads, max MLP, no staging barrier ----
// A thread's 4 priors own a contiguous 16B-aligned 44-float score slab:
// 11 independent float4 loads + int4 objinfo + float4 ov_prior all in flight.
__global__ void phaseD_kernel(const float* __restrict__ odm_locs,
                              const float* __restrict__ odm_scores,
                              const float* __restrict__ boxes,
                              const int* __restrict__ labels,
                              const float* __restrict__ priors,
                              const float* __restrict__ ov_prior,
                              const int* __restrict__ objinfo,
                              float* __restrict__ conf_neg,
                              int* __restrict__ n_pos,
                              double* __restrict__ acc){
  int b = blockIdx.y;
  int t = threadIdx.x;
  int p0 = (blockIdx.x*256 + t)*4;
  float locv = 0.0f, confpv = 0.0f; int posv = 0;
  if (p0 < Pn){                           // Pn%4==0 -> all 4 priors valid
    size_t bp0 = (size_t)b*Pn + p0;
    float4 sc4[11];
    const float4* src = (const float4*)(odm_scores + bp0*Cn);  // 16B-aligned
    #pragma unroll
    for (int i=0;i<11;i++) sc4[i] = src[i];
    int4   info4 = *(const int4*)(objinfo + bp0);
    float4 ovp4  = *(const float4*)(ov_prior + bp0);
    const float* sc = (const float*)sc4;
    const int*   infp = (const int*)&info4;
    const float* ovpp = (const float*)&ovp4;
    float cn[4];
    #pragma unroll
    for (int j=0;j<4;j++){
      int info = infp[j];
      int obj = info & 0xFF;
      bool ignored = (info & 256) != 0;
      int label = labels[b*On + obj];
      if (ovpp[j] < THRESHOLD_F) label = 0;
      bool pos = label > 0;
      const float* s = sc + j*Cn;
      float m = s[0];
      #pragma unroll
      for (int c=1;c<Cn;c++) m = fmaxf(m, s[c]);
      float se = 0.0f;
      #pragma unroll
      for (int c=0;c<Cn;c++) se += expf(s[c]-m);
      float conf = logf(se) - (s[label]-m);
      cn[j] = (pos || ignored) ? 0.0f : conf;
      if (pos){
        posv += 1; confpv += conf;
        size_t bp = bp0 + j;
        float4 pc = ((const float4*)priors)[p0+j];
        float4 g  = ((const float4*)odm_locs)[bp];
        float cx = g.x*pc.z/10.0f + pc.x;
        float cy = g.y*pc.w/10.0f + pc.y;
        float w  = expf(g.z/5.0f)*pc.z;
        float h  = expf(g.w/5.0f)*pc.w;
        float dx1 = cx - w/2.0f, dy1 = cy - h/2.0f;
        float dx2 = cx + w/2.0f, dy2 = cy + h/2.0f;
        const float* gt = boxes + ((size_t)b*On + obj)*4;
        float gx1=gt[0], gy1=gt[1], gx2=gt[2], gy2=gt[3];
        float ltx=fmaxf(dx1,gx1), lty=fmaxf(dy1,gy1);
        float rbx=fminf(dx2,gx2), rby=fminf(dy2,gy2);
        float iw=fmaxf(rbx-ltx,0.0f), ih=fmaxf(rby-lty,0.0f);
        float inter=iw*ih;
        float ap=(dx2-dx1)*(dy2-dy1);
        float ag=(gx2-gx1)*(gy2-gy1);
        float iou = inter/((ap+ag)-inter);
        float cpx=(dx1+dx2)/2.0f, cpy=(dy1+dy2)/2.0f;
        float cgx=(gx1+gx2)/2.0f, cgy=(gy1+gy2)/2.0f;
        float ddx=cpx-cgx, ddy=cpy-cgy;
        float inter_diag = ddx*ddx + ddy*ddy;
        float cltx=fminf(dx1,gx1), clty=fminf(dy1,gy1);
        float crbx=fmaxf(dx2,gx2), crby=fmaxf(dy2,gy2);
        float odx=crbx-cltx, ody=crby-clty;
        float outer_diag = odx*odx + ody*ody;
        float diou = fminf(fmaxf(iou - inter_diag/outer_diag, -1.0f), 1.0f);
        locv += 1.0f - diou;
      }
    }
    *(float4*)(conf_neg + bp0) = make_float4(cn[0],cn[1],cn[2],cn[3]);
  }
  __shared__ float sl[256]; __shared__ float scf[256]; __shared__ int sp[256];
  sl[t]=locv; scf[t]=confpv; sp[t]=posv;
  __syncthreads();
  for (int st=128; st>0; st>>=1){
    if (t<st){ sl[t]+=sl[t+st]; scf[t]+=scf[t+st]; sp[t]+=sp[t+st]; }
    __syncthreads();
  }
  if (t==0){
    if (sl[0]  != 0.0f) atomicAdd(&acc[1], (double)sl[0]);
    if (scf[0] != 0.0f) atomicAdd(&acc[2], (double)scf[0]);
    if (sp[0]  != 0)    atomicAdd(&n_pos[b], sp[0]);
  }
}

// ---- phase E (parallel radix-select, 3 rounds of 12/12/8 bits) ----
template<int ROUND>
__global__ void histE_kernel(const float* __restrict__ conf_neg,
                             const int* __restrict__ n_pos,
                             const unsigned* __restrict__ prefix,
                             unsigned* __restrict__ hist){
  int b = blockIdx.y, c = blockIdx.x, t = threadIdx.x;
  if (n_pos[b] <= 0) return;
  const int nb = (ROUND==2)?256:4096;
  __shared__ unsigned h[4096];
  for (int i=t;i<nb;i+=256) h[i]=0u;
  __syncthreads();
  unsigned pref = (ROUND==0)?0u:prefix[b];
  const float* cn = conf_neg + (size_t)b*Pn;
  int p0 = c*CHUNK, p1 = min(Pn, p0+CHUNK);
  for (int p=p0+t; p<p1; p+=256){
    unsigned key = __float_as_uint(cn[p]);
    if (ROUND==0){
      atomicAdd(&h[key>>20],1u);
    } else if (ROUND==1){
      if ((key>>20)==(pref>>20)) atomicAdd(&h[(key>>8)&0xFFFu],1u);
    } else {
      if ((key>>8)==(pref>>8)) atomicAdd(&h[key&0xFFu],1u);
    }
  }
  __syncthreads();
  unsigned* gh = hist + (size_t)b*4096;
  for (int i=t;i<nb;i+=256) if (h[i]) atomicAdd(&gh[i], h[i]);
}

template<int ROUND>
__global__ void scanE_kernel(const unsigned* __restrict__ hist,
                             const int* __restrict__ n_pos,
                             unsigned* __restrict__ prefix,
                             int* __restrict__ krem_st){
  int b = blockIdx.x, t = threadIdx.x;
  int K = 2*n_pos[b];
  if (K <= 0) return;
  const int nb = (ROUND==2)?256:4096;
  const int per = nb/256;
  const unsigned* gh = hist + (size_t)b*4096;
  unsigned cnt[per>0?per:1];
  unsigned ts = 0;
  #pragma unroll
  for (int i=0;i<per;i++){ cnt[i]=gh[t*per+i]; ts+=cnt[i]; }
  __shared__ unsigned sh[256];
  sh[t]=ts;
  __syncthreads();
  for (int off=1; off<256; off<<=1){
    unsigned v = (t+off<256)? sh[t+off]:0u;   // read (after barrier)
    __syncthreads();
    sh[t]+=v;                                  // write
    __syncthreads();
  }
  int krem = (ROUND==0)? K : krem_st[b];
  unsigned incl = sh[t];           // count of keys in bins >= this thread's lowest
  unsigned above = incl - ts;      // count in strictly-higher threads' bins
  if ((int)above < krem && krem <= (int)incl){
    int acc = (int)above;
    #pragma unroll
    for (int i=per-1;i>=0;i--){
      acc += (int)cnt[i];
      if (acc >= krem){
        unsigned sel = (unsigned)(t*per+i);
        int krem_new = krem - (acc - (int)cnt[i]);
        if (ROUND==0)      prefix[b]  = sel<<20;
        else if (ROUND==1) prefix[b] |= sel<<8;
        else               prefix[b] |= sel;
        krem_st[b]=krem_new;
        break;
      }
    }
  }
}

// Final: sum = sum(v > t) + krem * t  (exact "first K of descending sort")
__global__ void finalE_kernel(const float* __restrict__ conf_neg,
                              const int* __restrict__ n_pos,
                              const unsigned* __restrict__ prefix,
                              const int* __restrict__ krem_st,
                              double* __restrict__ acc){
  int b = blockIdx.y, c = blockIdx.x, t = threadIdx.x;
  int K = 2*n_pos[b];
  if (K <= 0) return;
  const float* cn = conf_neg + (size_t)b*Pn;
  int p0=c*CHUNK, p1=min(Pn,p0+CHUNK);
  float s=0.0f;
  if (K >= Pn){
    for (int p=p0+t;p<p1;p+=256) s += cn[p];
  } else {
    unsigned tb = prefix[b];
    for (int p=p0+t;p<p1;p+=256){
      float v = cn[p];
      if (__float_as_uint(v) > tb) s += v;
    }
  }
  __shared__ float sr[256];
  sr[t]=s; __syncthreads();
  for (int st=128;st>0;st>>=1){ if(t<st) sr[t]+=sr[t+st]; __syncthreads(); }
  if (t==0){
    double add = (double)sr[0];
    if (c==0 && K < Pn) add += (double)krem_st[b] * (double)__uint_as_float(prefix[b]);
    if (add != 0.0) atomicAdd(&acc[3], add);
  }
}

// ---- final combine ----
__global__ void final_kernel(const int* __restrict__ n_pos,
                             const double* __restrict__ acc,
                             float* __restrict__ out){
  if (threadIdx.x==0 && blockIdx.x==0){
    int tp = 0;
    for (int b=0;b<Bn;b++) tp += n_pos[b];
    float total = (float)tp;
    float conf_loss = (float)(acc[3] + acc[2]) / total;
    float loc_loss  = (float)acc[1] / total;
    float seg_loss  = -(float)acc[0];
    out[0] = conf_loss + loc_loss + seg_loss;
  }
}

extern "C" void kernel_launch(void* const* d_in, const int* in_sizes, int n_in,
                              void* d_out, int out_size, void* d_ws, size_t ws_size,
                              hipStream_t stream) {
  const float* odm_locs   = (const float*)d_in[0];
  const float* odm_scores = (const float*)d_in[1];
  const float* att        = (const float*)d_in[2];
  const float* boxes      = (const float*)d_in[3];
  const int*   labels     = (const int*)d_in[4];
  const float* ign        = (const float*)d_in[5];
  const float* priors     = (const float*)d_in[6];
  float* out = (float*)d_out;

  size_t np = (size_t)Bn * Pn;
  float* ov_prior  = (float*)d_ws;                 // B*P f32
  int*   objinfo   = (int*)(ov_prior + np);        // B*P i32 (bits0-7 obj, bit8 ignored)
  float* conf_neg  = (float*)(objinfo + np);       // B*P f32
  float* ov_obj    = conf_neg + np;                // B*O f32
  int*   prior_obj = (int*)(ov_obj + (size_t)Bn*On); // B*O i32
  int*   n_pos     = prior_obj + (size_t)Bn*On;    // B i32
  double* acc      = (double*)(n_pos + Bn);        // [seg, loc, conf_pos, conf_hard]

  // radix-select scratch lives in the ov_prior region (dead after phaseD):
  unsigned* histB  = (unsigned*)ov_prior;
  unsigned* prefix = histB + 3*(size_t)Bn*4096;
  int*      krem   = (int*)(prefix + Bn);

  // zero only the accumulators (all big arrays are fully rewritten each call)
  hipMemsetAsync(n_pos, 0, Bn*sizeof(int) + 4*sizeof(double), stream);

  int pblocks = (Pn + 255) / 256;
  int dblocks = (Pn/4 + 255) / 256;
  seg_kernel  <<<(ATT_N+255)/256, 256, 0, stream>>>(att, acc);
  phaseA_kernel<<<dim3(pblocks, Bn), 256, 0, stream>>>(boxes, ign, priors, ov_prior, objinfo);
  phaseB_kernel<<<dim3(On, Bn),      256, 0, stream>>>(boxes, priors, ov_obj, prior_obj);
  phaseC_kernel<<<1, 64, 0, stream>>>(ov_obj, prior_obj, ov_prior, objinfo);
  phaseD_kernel<<<dim3(dblocks, Bn), 256, 0, stream>>>(odm_locs, odm_scores, boxes, labels,
                                                       priors, ov_prior, objinfo,
                                                       conf_neg, n_pos, acc);
  // ov_prior is dead from here; reuse as radix scratch.
  hipMemsetAsync(histB, 0, 3*(size_t)Bn*4096*sizeof(unsigned), stream);
  histE_kernel<0><<<dim3(CHn, Bn), 256, 0, stream>>>(conf_neg, n_pos, prefix, histB);
  scanE_kernel<0><<<Bn, 256, 0, stream>>>(histB, n_pos, prefix, krem);
  histE_kernel<1><<<dim3(CHn, Bn), 256, 0, stream>>>(conf_neg, n_pos, prefix, histB + (size_t)Bn*4096);
  scanE_kernel<1><<<Bn, 256, 0, stream>>>(histB + (size_t)Bn*4096, n_pos, prefix, krem);
  histE_kernel<2><<<dim3(CHn, Bn), 256, 0, stream>>>(conf_neg, n_pos, prefix, histB + 2*(size_t)Bn*4096);
  scanE_kernel<2><<<Bn, 256, 0, stream>>>(histB + 2*(size_t)Bn*4096, n_pos, prefix, krem);
  finalE_kernel<<<dim3(CHn, Bn), 256, 0, stream>>>(conf_neg, n_pos, prefix, krem, acc);
  final_kernel<<<1, 64, 0, stream>>>(n_pos, acc, out);
}

// Round 10
// 289.132 us; speedup vs baseline: 1.3192x; 1.0298x over previous
//
#include <hip/hip_runtime.h>
#include <math.h>

#define Bn 32
#define Pn 42840
#define On 64
#define NIn 8
#define Cn 11
#define ATT_N (32*56*96)
#define THRESHOLD_F 0.4f
#define THETA_F 0.1f
#define CHn 16
#define CHUNK ((Pn + CHn - 1)/CHn)

// IoU of two corner-format boxes, mirroring the jnp op order exactly.
__device__ __forceinline__ float iou_c(float ax1,float ay1,float ax2,float ay2,
                                       float bx1,float by1,float bx2,float by2){
  float ltx=fmaxf(ax1,bx1), lty=fmaxf(ay1,by1);
  float rbx=fminf(ax2,bx2), rby=fminf(ay2,by2);
  float w=fmaxf(rbx-ltx,0.0f), h=fmaxf(rby-lty,0.0f);
  float inter=w*h;
  float aa=(ax2-ax1)*(ay2-ay1);
  float ab=(bx2-bx1)*(by2-by1);
  return inter/((aa+ab)-inter);
}

// ---- seg loss: sum of max(log1p(-a), -100); negated at the end ----
__global__ void seg_kernel(const float* __restrict__ att, double* __restrict__ acc){
  int i = blockIdx.x*256 + threadIdx.x;
  float v = 0.0f;
  if (i < ATT_N) v = fmaxf(log1pf(-att[i]), -100.0f);
  __shared__ float s[256];
  int t = threadIdx.x;
  s[t]=v; __syncthreads();
  for (int st=128; st>0; st>>=1){ if (t<st) s[t]+=s[t+st]; __syncthreads(); }
  if (t==0) atomicAdd(&acc[0], (double)s[0]);
}

// ---- phase A: per (b,p): max/argmax over objects (first occurrence), ignored flag ----
__global__ void phaseA_kernel(const float* __restrict__ boxes,
                              const float* __restrict__ ign,
                              const float* __restrict__ priors,
                              float* __restrict__ ov_prior,
                              int* __restrict__ objinfo){
  __shared__ float sb[On*4];
  __shared__ float si[NIn*4];
  int b = blockIdx.y;
  int t = threadIdx.x;
  if (t < On*4)  sb[t] = boxes[(size_t)b*On*4 + t];
  if (t < NIn*4) si[t] = ign[(size_t)b*NIn*4 + t];
  __syncthreads();
  int p = blockIdx.x*256 + t;
  if (p >= Pn) return;
  float4 pc = ((const float4*)priors)[p];
  float px1 = pc.x - pc.z/2.0f, py1 = pc.y - pc.w/2.0f;
  float px2 = pc.x + pc.z/2.0f, py2 = pc.y + pc.w/2.0f;
  float best = -1.0f; int besto = 0;
  #pragma unroll 4
  for (int o=0;o<On;o++){
    float v = iou_c(sb[4*o],sb[4*o+1],sb[4*o+2],sb[4*o+3], px1,py1,px2,py2);
    if (v > best){ best = v; besto = o; }   // strict > keeps first argmax
  }
  float ig = iou_c(si[0],si[1],si[2],si[3], px1,py1,px2,py2);
  #pragma unroll
  for (int o=1;o<NIn;o++)
    ig = fmaxf(ig, iou_c(si[4*o],si[4*o+1],si[4*o+2],si[4*o+3], px1,py1,px2,py2));
  size_t bp = (size_t)b*Pn + p;
  ov_prior[bp] = best;
  objinfo[bp]  = besto | ((ig >= THETA_F) ? 256 : 0);
}

// ---- phase B: per (b,o): max/argmax over P (first occurrence via packed key) ----
__global__ void phaseB_kernel(const float* __restrict__ boxes,
                              const float* __restrict__ priors,
                              float* __restrict__ ov_obj,
                              int* __restrict__ prior_obj){
  int b = blockIdx.y, o = blockIdx.x, t = threadIdx.x;
  const float* bx = boxes + ((size_t)b*On + o)*4;
  float ax1=bx[0], ay1=bx[1], ax2=bx[2], ay2=bx[3];
  unsigned long long key = 0ull;   // loses to any real key (low32=~p > 0)
  for (int p=t; p<Pn; p+=256){
    float4 pc = ((const float4*)priors)[p];
    float px1 = pc.x - pc.z/2.0f, py1 = pc.y - pc.w/2.0f;
    float px2 = pc.x + pc.z/2.0f, py2 = pc.y + pc.w/2.0f;
    float v = iou_c(ax1,ay1,ax2,ay2, px1,py1,px2,py2);  // v >= 0 -> bits ordered
    unsigned long long k = ((unsigned long long)__float_as_uint(v) << 32)
                         | (unsigned long long)(0xFFFFFFFFu - (unsigned)p);
    if (k > key) key = k;
  }
  __shared__ unsigned long long sk[256];
  sk[t] = key; __syncthreads();
  for (int st=128; st>0; st>>=1){
    if (t<st && sk[t+st] > sk[t]) sk[t] = sk[t+st];
    __syncthreads();
  }
  if (t==0){
    ov_obj[(size_t)b*On+o]   = __uint_as_float((unsigned)(sk[0] >> 32));
    prior_obj[(size_t)b*On+o]= (int)(0xFFFFFFFFu - (unsigned)(sk[0] & 0xFFFFFFFFu));
  }
}

// ---- phase C: sequential per-batch scatter (set 1.0; last-write-wins rank) ----
__global__ void phaseC_kernel(const float* __restrict__ ov_obj,
                              const int* __restrict__ prior_obj,
                              float* __restrict__ ov_prior,
                              int* __restrict__ objinfo){
  int b = threadIdx.x;
  if (b >= Bn) return;
  int rank = -1;
  for (int o=0;o<On;o++){
    if (ov_obj[(size_t)b*On+o] > 0.0f){
      rank++;                                   // jranks = cumsum(valid)-1
      int p = prior_obj[(size_t)b*On+o];
      size_t bp = (size_t)b*Pn + p;
      ov_prior[bp] = 1.0f;
      objinfo[bp] = (objinfo[bp] & 256) | rank; // ascending o => overwrite == max(jr)
    }
  }
}

// ---- phase D: 4 priors/thread, direct loads, max MLP, all-register scores ----
// s[label] is extracted via an unrolled compare-select (label is runtime;
// dynamic indexing into the register array would spill it to scratch).
__global__ void phaseD_kernel(const float* __restrict__ odm_locs,
                              const float* __restrict__ odm_scores,
                              const float* __restrict__ boxes,
                              const int* __restrict__ labels,
                              const float* __restrict__ priors,
                              const float* __restrict__ ov_prior,
                              const int* __restrict__ objinfo,
                              float* __restrict__ conf_neg,
                              int* __restrict__ n_pos,
                              double* __restrict__ acc){
  int b = blockIdx.y;
  int t = threadIdx.x;
  int p0 = (blockIdx.x*256 + t)*4;
  float locv = 0.0f, confpv = 0.0f; int posv = 0;
  if (p0 < Pn){                           // Pn%4==0 -> all 4 priors valid
    size_t bp0 = (size_t)b*Pn + p0;
    float4 sc4[11];
    const float4* src = (const float4*)(odm_scores + bp0*Cn);  // 16B-aligned
    #pragma unroll
    for (int i=0;i<11;i++) sc4[i] = src[i];
    int4   info4 = *(const int4*)(objinfo + bp0);
    float4 ovp4  = *(const float4*)(ov_prior + bp0);
    const float* sc = (const float*)sc4;   // constant indices only (post-unroll)
    float cn[4];
    #pragma unroll
    for (int j=0;j<4;j++){
      int info = (&info4.x)[j];
      int obj = info & 0xFF;
      bool ignored = (info & 256) != 0;
      int label = labels[b*On + obj];
      if ((&ovp4.x)[j] < THRESHOLD_F) label = 0;
      bool pos = label > 0;
      float m = sc[j*Cn];
      #pragma unroll
      for (int c=1;c<Cn;c++) m = fmaxf(m, sc[j*Cn+c]);
      float se = 0.0f, slab = 0.0f;
      #pragma unroll
      for (int c=0;c<Cn;c++){
        float v = sc[j*Cn+c];
        se += expf(v-m);
        if (c == label) slab = v;          // c is compile-time -> cndmask chain
      }
      float conf = logf(se) - (slab-m);
      cn[j] = (pos || ignored) ? 0.0f : conf;
      if (pos){
        posv += 1; confpv += conf;
        size_t bp = bp0 + j;
        float4 pc = ((const float4*)priors)[p0+j];
        float4 g  = ((const float4*)odm_locs)[bp];
        float cx = g.x*pc.z/10.0f + pc.x;
        float cy = g.y*pc.w/10.0f + pc.y;
        float w  = expf(g.z/5.0f)*pc.z;
        float h  = expf(g.w/5.0f)*pc.w;
        float dx1 = cx - w/2.0f, dy1 = cy - h/2.0f;
        float dx2 = cx + w/2.0f, dy2 = cy + h/2.0f;
        const float* gt = boxes + ((size_t)b*On + obj)*4;
        float gx1=gt[0], gy1=gt[1], gx2=gt[2], gy2=gt[3];
        float ltx=fmaxf(dx1,gx1), lty=fmaxf(dy1,gy1);
        float rbx=fminf(dx2,gx2), rby=fminf(dy2,gy2);
        float iw=fmaxf(rbx-ltx,0.0f), ih=fmaxf(rby-lty,0.0f);
        float inter=iw*ih;
        float ap=(dx2-dx1)*(dy2-dy1);
        float ag=(gx2-gx1)*(gy2-gy1);
        float iou = inter/((ap+ag)-inter);
        float cpx=(dx1+dx2)/2.0f, cpy=(dy1+dy2)/2.0f;
        float cgx=(gx1+gx2)/2.0f, cgy=(gy1+gy2)/2.0f;
        float ddx=cpx-cgx, ddy=cpy-cgy;
        float inter_diag = ddx*ddx + ddy*ddy;
        float cltx=fminf(dx1,gx1), clty=fminf(dy1,gy1);
        float crbx=fmaxf(dx2,gx2), crby=fmaxf(dy2,gy2);
        float odx=crbx-cltx, ody=crby-clty;
        float outer_diag = odx*odx + ody*ody;
        float diou = fminf(fmaxf(iou - inter_diag/outer_diag, -1.0f), 1.0f);
        locv += 1.0f - diou;
      }
    }
    *(float4*)(conf_neg + bp0) = make_float4(cn[0],cn[1],cn[2],cn[3]);
  }
  __shared__ float sl[256]; __shared__ float scf[256]; __shared__ int sp[256];
  sl[t]=locv; scf[t]=confpv; sp[t]=posv;
  __syncthreads();
  for (int st=128; st>0; st>>=1){
    if (t<st){ sl[t]+=sl[t+st]; scf[t]+=scf[t+st]; sp[t]+=sp[t+st]; }
    __syncthreads();
  }
  if (t==0){
    if (sl[0]  != 0.0f) atomicAdd(&acc[1], (double)sl[0]);
    if (scf[0] != 0.0f) atomicAdd(&acc[2], (double)scf[0]);
    if (sp[0]  != 0)    atomicAdd(&n_pos[b], sp[0]);
  }
}

// ---- phase E (parallel radix-select, 3 rounds of 12/12/8 bits) ----
template<int ROUND>
__global__ void histE_kernel(const float* __restrict__ conf_neg,
                             const int* __restrict__ n_pos,
                             const unsigned* __restrict__ prefix,
                             unsigned* __restrict__ hist){
  int b = blockIdx.y, c = blockIdx.x, t = threadIdx.x;
  if (n_pos[b] <= 0) return;
  const int nb = (ROUND==2)?256:4096;
  __shared__ unsigned h[4096];
  for (int i=t;i<nb;i+=256) h[i]=0u;
  __syncthreads();
  unsigned pref = (ROUND==0)?0u:prefix[b];
  const float* cn = conf_neg + (size_t)b*Pn;
  int p0 = c*CHUNK, p1 = min(Pn, p0+CHUNK);
  for (int p=p0+t; p<p1; p+=256){
    unsigned key = __float_as_uint(cn[p]);
    if (ROUND==0){
      atomicAdd(&h[key>>20],1u);
    } else if (ROUND==1){
      if ((key>>20)==(pref>>20)) atomicAdd(&h[(key>>8)&0xFFFu],1u);
    } else {
      if ((key>>8)==(pref>>8)) atomicAdd(&h[key&0xFFu],1u);
    }
  }
  __syncthreads();
  unsigned* gh = hist + (size_t)b*4096;
  for (int i=t;i<nb;i+=256) if (h[i]) atomicAdd(&gh[i], h[i]);
}

template<int ROUND>
__global__ void scanE_kernel(const unsigned* __restrict__ hist,
                             const int* __restrict__ n_pos,
                             unsigned* __restrict__ prefix,
                             int* __restrict__ krem_st){
  int b = blockIdx.x, t = threadIdx.x;
  int K = 2*n_pos[b];
  if (K <= 0) return;
  const int nb = (ROUND==2)?256:4096;
  const int per = nb/256;
  const unsigned* gh = hist + (size_t)b*4096;
  unsigned cnt[per>0?per:1];
  unsigned ts = 0;
  #pragma unroll
  for (int i=0;i<per;i++){ cnt[i]=gh[t*per+i]; ts+=cnt[i]; }
  __shared__ unsigned sh[256];
  sh[t]=ts;
  __syncthreads();
  for (int off=1; off<256; off<<=1){
    unsigned v = (t+off<256)? sh[t+off]:0u;   // read (after barrier)
    __syncthreads();
    sh[t]+=v;                                  // write
    __syncthreads();
  }
  int krem = (ROUND==0)? K : krem_st[b];
  unsigned incl = sh[t];           // count of keys in bins >= this thread's lowest
  unsigned above = incl - ts;      // count in strictly-higher threads' bins
  if ((int)above < krem && krem <= (int)incl){
    int acc = (int)above;
    #pragma unroll
    for (int i=per-1;i>=0;i--){
      acc += (int)cnt[i];
      if (acc >= krem){
        unsigned sel = (unsigned)(t*per+i);
        int krem_new = krem - (acc - (int)cnt[i]);
        if (ROUND==0)      prefix[b]  = sel<<20;
        else if (ROUND==1) prefix[b] |= sel<<8;
        else               prefix[b] |= sel;
        krem_st[b]=krem_new;
        break;
      }
    }
  }
}

// Final: sum = sum(v > t) + krem * t  (exact "first K of descending sort")
__global__ void finalE_kernel(const float* __restrict__ conf_neg,
                              const int* __restrict__ n_pos,
                              const unsigned* __restrict__ prefix,
                              const int* __restrict__ krem_st,
                              double* __restrict__ acc){
  int b = blockIdx.y, c = blockIdx.x, t = threadIdx.x;
  int K = 2*n_pos[b];
  if (K <= 0) return;
  const float* cn = conf_neg + (size_t)b*Pn;
  int p0=c*CHUNK, p1=min(Pn,p0+CHUNK);
  float s=0.0f;
  if (K >= Pn){
    for (int p=p0+t;p<p1;p+=256) s += cn[p];
  } else {
    unsigned tb = prefix[b];
    for (int p=p0+t;p<p1;p+=256){
      float v = cn[p];
      if (__float_as_uint(v) > tb) s += v;
    }
  }
  __shared__ float sr[256];
  sr[t]=s; __syncthreads();
  for (int st=128;st>0;st>>=1){ if(t<st) sr[t]+=sr[t+st]; __syncthreads(); }
  if (t==0){
    double add = (double)sr[0];
    if (c==0 && K < Pn) add += (double)krem_st[b] * (double)__uint_as_float(prefix[b]);
    if (add != 0.0) atomicAdd(&acc[3], add);
  }
}

// ---- final combine ----
__global__ void final_kernel(const int* __restrict__ n_pos,
                             const double* __restrict__ acc,
                             float* __restrict__ out){
  if (threadIdx.x==0 && blockIdx.x==0){
    int tp = 0;
    for (int b=0;b<Bn;b++) tp += n_pos[b];
    float total = (float)tp;
    float conf_loss = (float)(acc[3] + acc[2]) / total;
    float loc_loss  = (float)acc[1] / total;
    float seg_loss  = -(float)acc[0];
    out[0] = conf_loss + loc_loss + seg_loss;
  }
}

extern "C" void kernel_launch(void* const* d_in, const int* in_sizes, int n_in,
                              void* d_out, int out_size, void* d_ws, size_t ws_size,
                              hipStream_t stream) {
  const float* odm_locs   = (const float*)d_in[0];
  const float* odm_scores = (const float*)d_in[1];
  const float* att        = (const float*)d_in[2];
  const float* boxes      = (const float*)d_in[3];
  const int*   labels     = (const int*)d_in[4];
  const float* ign        = (const float*)d_in[5];
  const float* priors     = (const float*)d_in[6];
  float* out = (float*)d_out;

  size_t np = (size_t)Bn * Pn;
  float* ov_prior  = (float*)d_ws;                 // B*P f32
  int*   objinfo   = (int*)(ov_prior + np);        // B*P i32 (bits0-7 obj, bit8 ignored)
  float* conf_neg  = (float*)(objinfo + np);       // B*P f32
  float* ov_obj    = conf_neg + np;                // B*O f32
  int*   prior_obj = (int*)(ov_obj + (size_t)Bn*On); // B*O i32
  int*   n_pos     = prior_obj + (size_t)Bn*On;    // B i32
  double* acc      = (double*)(n_pos + Bn);        // [seg, loc, conf_pos, conf_hard]

  // radix-select scratch lives in the ov_prior region (dead after phaseD):
  unsigned* histB  = (unsigned*)ov_prior;
  unsigned* prefix = histB + 3*(size_t)Bn*4096;
  int*      krem   = (int*)(prefix + Bn);

  // zero only the accumulators (all big arrays are fully rewritten each call)
  hipMemsetAsync(n_pos, 0, Bn*sizeof(int) + 4*sizeof(double), stream);

  int pblocks = (Pn + 255) / 256;
  int dblocks = (Pn/4 + 255) / 256;
  seg_kernel  <<<(ATT_N+255)/256, 256, 0, stream>>>(att, acc);
  phaseA_kernel<<<dim3(pblocks, Bn), 256, 0, stream>>>(boxes, ign, priors, ov_prior, objinfo);
  phaseB_kernel<<<dim3(On, Bn),      256, 0, stream>>>(boxes, priors, ov_obj, prior_obj);
  phaseC_kernel<<<1, 64, 0, stream>>>(ov_obj, prior_obj, ov_prior, objinfo);
  phaseD_kernel<<<dim3(dblocks, Bn), 256, 0, stream>>>(odm_locs, odm_scores, boxes, labels,
                                                       priors, ov_prior, objinfo,
                                                       conf_neg, n_pos, acc);
  // ov_prior is dead from here; reuse as radix scratch.
  hipMemsetAsync(histB, 0, 3*(size_t)Bn*4096*sizeof(unsigned), stream);
  histE_kernel<0><<<dim3(CHn, Bn), 256, 0, stream>>>(conf_neg, n_pos, prefix, histB);
  scanE_kernel<0><<<Bn, 256, 0, stream>>>(histB, n_pos, prefix, krem);
  histE_kernel<1><<<dim3(CHn, Bn), 256, 0, stream>>>(conf_neg, n_pos, prefix, histB + (size_t)Bn*4096);
  scanE_kernel<1><<<Bn, 256, 0, stream>>>(histB + (size_t)Bn*4096, n_pos, prefix, krem);
  histE_kernel<2><<<dim3(CHn, Bn), 256, 0, stream>>>(conf_neg, n_pos, prefix, histB + 2*(size_t)Bn*4096);
  scanE_kernel<2><<<Bn, 256, 0, stream>>>(histB + 2*(size_t)Bn*4096, n_pos, prefix, krem);
  finalE_kernel<<<dim3(CHn, Bn), 256, 0, stream>>>(conf_neg, n_pos, prefix, krem, acc);
  final_kernel<<<1, 64, 0, stream>>>(n_pos, acc, out);
}

// Round 11
// 238.702 us; speedup vs baseline: 1.5979x; 1.2113x over previous
//
#include <hip/hip_runtime.h>
#include <math.h>

#define Bn 32
#define Pn 42840
#define On 64
#define NIn 8
#define Cn 11
#define ATT_N (32*56*96)
#define THRESHOLD_F 0.4f
#define THETA_F 0.1f
#define CHn 16
#define CHUNK ((Pn + CHn - 1)/CHn)
#define OC 8            /* objects per phaseB block */
#define PCn 8           /* prior chunks; Pn = 8*5355 exactly */
#define PCH (Pn/PCn)

// ---- seg loss: sum of max(log1p(-a), -100); negated at the end ----
__global__ void seg_kernel(const float* __restrict__ att, double* __restrict__ acc){
  int i = blockIdx.x*256 + threadIdx.x;
  float v = 0.0f;
  if (i < ATT_N) v = fmaxf(log1pf(-att[i]), -100.0f);
  __shared__ float s[256];
  int t = threadIdx.x;
  s[t]=v; __syncthreads();
  for (int st=128; st>0; st>>=1){ if (t<st) s[t]+=s[t+st]; __syncthreads(); }
  if (t==0) atomicAdd(&acc[0], (double)s[0]);
}

// ---- phase A: per (b,p) argmax over objects via cross-mult; 2 divisions total ----
__global__ void phaseA_kernel(const float* __restrict__ boxes,
                              const float* __restrict__ ign,
                              const float* __restrict__ priors,
                              float* __restrict__ ov_prior,
                              int* __restrict__ objinfo){
  __shared__ float sb[On*4];
  __shared__ float si[NIn*4];
  __shared__ float sa[On];
  __shared__ float sia[NIn];
  int b = blockIdx.y;
  int t = threadIdx.x;
  if (t < On*4)  sb[t] = boxes[(size_t)b*On*4 + t];
  if (t < NIn*4) si[t] = ign[(size_t)b*NIn*4 + t];
  __syncthreads();
  if (t < On)  sa[t]  = (sb[4*t+2]-sb[4*t])*(sb[4*t+3]-sb[4*t+1]);
  if (t < NIn) sia[t] = (si[4*t+2]-si[4*t])*(si[4*t+3]-si[4*t+1]);
  __syncthreads();
  int p = blockIdx.x*256 + t;
  if (p >= Pn) return;
  float4 pc = ((const float4*)priors)[p];
  float px1 = pc.x - pc.z/2.0f, py1 = pc.y - pc.w/2.0f;
  float px2 = pc.x + pc.z/2.0f, py2 = pc.y + pc.w/2.0f;
  float ab = (px2-px1)*(py2-py1);
  // argmax over objects: track (inter, union) winner via cross-multiplied compare
  float bi = -1.0f, bu = 1.0f; int bo = 0;
  #pragma unroll 4
  for (int o=0;o<On;o++){
    float ltx=fmaxf(sb[4*o],px1),   lty=fmaxf(sb[4*o+1],py1);
    float rbx=fminf(sb[4*o+2],px2), rby=fminf(sb[4*o+3],py2);
    float w=fmaxf(rbx-ltx,0.0f), h=fmaxf(rby-lty,0.0f);
    float inter=w*h;
    float uni=(sa[o]+ab)-inter;
    if (inter*bu > bi*uni){ bi=inter; bu=uni; bo=o; }  // strict > keeps first
  }
  float ii = -1.0f, iu = 1.0f;
  #pragma unroll
  for (int o=0;o<NIn;o++){
    float ltx=fmaxf(si[4*o],px1),   lty=fmaxf(si[4*o+1],py1);
    float rbx=fminf(si[4*o+2],px2), rby=fminf(si[4*o+3],py2);
    float w=fmaxf(rbx-ltx,0.0f), h=fmaxf(rby-lty,0.0f);
    float inter=w*h;
    float uni=(sia[o]+ab)-inter;
    if (inter*iu > ii*uni){ ii=inter; iu=uni; }
  }
  float best = bi/bu;        // one exact division
  float ig   = ii/iu;        // one exact division
  size_t bp = (size_t)b*Pn + p;
  ov_prior[bp] = best;
  objinfo[bp]  = bo | ((ig >= THETA_F) ? 256 : 0);
}

// ---- phase B: per (b,o) argmax over P; 8 objects/block, cross-mult inner loop,
//      one division per (thread,object), u64 key wave-reduce + global atomicMax ----
__global__ void phaseB_kernel(const float* __restrict__ boxes,
                              const float* __restrict__ priors,
                              unsigned long long* __restrict__ key_obj){
  int c = blockIdx.x, og = blockIdx.y, b = blockIdx.z, t = threadIdx.x;
  float ox1[OC], oy1[OC], ox2[OC], oy2[OC], oa[OC];
  const float4* bx = (const float4*)(boxes + ((size_t)b*On + og*OC)*4);
  #pragma unroll
  for (int j=0;j<OC;j++){
    float4 v = bx[j];
    ox1[j]=v.x; oy1[j]=v.y; ox2[j]=v.z; oy2[j]=v.w;
    oa[j]=(v.z-v.x)*(v.w-v.y);
  }
  float bi[OC], bu[OC]; unsigned bp_[OC];
  #pragma unroll
  for (int j=0;j<OC;j++){ bi[j]=-1.0f; bu[j]=1.0f; bp_[j]=0u; }
  int p0 = c*PCH;
  for (int p=p0+t; p<p0+PCH; p+=256){      // PCH divides evenly; all lanes iterate
    float4 pc = ((const float4*)priors)[p];
    float px1 = pc.x - pc.z/2.0f, py1 = pc.y - pc.w/2.0f;
    float px2 = pc.x + pc.z/2.0f, py2 = pc.y + pc.w/2.0f;
    float ab = (px2-px1)*(py2-py1);
    #pragma unroll
    for (int j=0;j<OC;j++){
      float ltx=fmaxf(ox1[j],px1), lty=fmaxf(oy1[j],py1);
      float rbx=fminf(ox2[j],px2), rby=fminf(oy2[j],py2);
      float w=fmaxf(rbx-ltx,0.0f), h=fmaxf(rby-lty,0.0f);
      float inter=w*h;
      float uni=(oa[j]+ab)-inter;
      if (inter*bu[j] > bi[j]*uni){ bi[j]=inter; bu[j]=uni; bp_[j]=(unsigned)p; }
    }
  }
  #pragma unroll
  for (int j=0;j<OC;j++){
    float iou = bi[j]/bu[j];               // one exact division per object
    unsigned long long key = ((unsigned long long)__float_as_uint(iou)<<32)
                           | (unsigned long long)(0xFFFFFFFFu - bp_[j]);
    #pragma unroll
    for (int d=32; d>0; d>>=1){
      unsigned long long o2 = __shfl_xor(key, d, 64);
      if (o2 > key) key = o2;
    }
    if ((t & 63) == 0)
      atomicMax(&key_obj[(size_t)b*On + og*OC + j], key);
  }
}

// ---- phase C: sequential per-batch scatter (set 1.0; last-write-wins rank) ----
__global__ void phaseC_kernel(const unsigned long long* __restrict__ key_obj,
                              float* __restrict__ ov_prior,
                              int* __restrict__ objinfo){
  int b = threadIdx.x;
  if (b >= Bn) return;
  int rank = -1;
  for (int o=0;o<On;o++){
    unsigned long long k = key_obj[(size_t)b*On+o];
    if ((unsigned)(k>>32) > 0u){            // iou > 0  <=> valid
      rank++;                               // jranks = cumsum(valid)-1
      int p = (int)(0xFFFFFFFFu - (unsigned)(k & 0xFFFFFFFFu));
      size_t bp = (size_t)b*Pn + p;
      ov_prior[bp] = 1.0f;
      objinfo[bp] = (objinfo[bp] & 256) | rank; // ascending o => overwrite == max(jr)
    }
  }
}

// ---- phase D: 4 priors/thread, direct loads, max MLP, all-register scores ----
__global__ void phaseD_kernel(const float* __restrict__ odm_locs,
                              const float* __restrict__ odm_scores,
                              const float* __restrict__ boxes,
                              const int* __restrict__ labels,
                              const float* __restrict__ priors,
                              const float* __restrict__ ov_prior,
                              const int* __restrict__ objinfo,
                              float* __restrict__ conf_neg,
                              int* __restrict__ n_pos,
                              double* __restrict__ acc){
  int b = blockIdx.y;
  int t = threadIdx.x;
  int p0 = (blockIdx.x*256 + t)*4;
  float locv = 0.0f, confpv = 0.0f; int posv = 0;
  if (p0 < Pn){                           // Pn%4==0 -> all 4 priors valid
    size_t bp0 = (size_t)b*Pn + p0;
    float4 sc4[11];
    const float4* src = (const float4*)(odm_scores + bp0*Cn);  // 16B-aligned
    #pragma unroll
    for (int i=0;i<11;i++) sc4[i] = src[i];
    int4   info4 = *(const int4*)(objinfo + bp0);
    float4 ovp4  = *(const float4*)(ov_prior + bp0);
    const float* sc = (const float*)sc4;   // constant indices only (post-unroll)
    float cn[4];
    #pragma unroll
    for (int j=0;j<4;j++){
      int info = (&info4.x)[j];
      int obj = info & 0xFF;
      bool ignored = (info & 256) != 0;
      int label = labels[b*On + obj];
      if ((&ovp4.x)[j] < THRESHOLD_F) label = 0;
      bool pos = label > 0;
      float m = sc[j*Cn];
      #pragma unroll
      for (int c=1;c<Cn;c++) m = fmaxf(m, sc[j*Cn+c]);
      float se = 0.0f, slab = 0.0f;
      #pragma unroll
      for (int c=0;c<Cn;c++){
        float v = sc[j*Cn+c];
        se += expf(v-m);
        if (c == label) slab = v;          // c is compile-time -> cndmask chain
      }
      float conf = logf(se) - (slab-m);
      cn[j] = (pos || ignored) ? 0.0f : conf;
      if (pos){
        posv += 1; confpv += conf;
        size_t bp = bp0 + j;
        float4 pc = ((const float4*)priors)[p0+j];
        float4 g  = ((const float4*)odm_locs)[bp];
        float cx = g.x*pc.z/10.0f + pc.x;
        float cy = g.y*pc.w/10.0f + pc.y;
        float w  = expf(g.z/5.0f)*pc.z;
        float h  = expf(g.w/5.0f)*pc.w;
        float dx1 = cx - w/2.0f, dy1 = cy - h/2.0f;
        float dx2 = cx + w/2.0f, dy2 = cy + h/2.0f;
        const float* gt = boxes + ((size_t)b*On + obj)*4;
        float gx1=gt[0], gy1=gt[1], gx2=gt[2], gy2=gt[3];
        float ltx=fmaxf(dx1,gx1), lty=fmaxf(dy1,gy1);
        float rbx=fminf(dx2,gx2), rby=fminf(dy2,gy2);
        float iw=fmaxf(rbx-ltx,0.0f), ih=fmaxf(rby-lty,0.0f);
        float inter=iw*ih;
        float ap=(dx2-dx1)*(dy2-dy1);
        float ag=(gx2-gx1)*(gy2-gy1);
        float iou = inter/((ap+ag)-inter);
        float cpx=(dx1+dx2)/2.0f, cpy=(dy1+dy2)/2.0f;
        float cgx=(gx1+gx2)/2.0f, cgy=(gy1+gy2)/2.0f;
        float ddx=cpx-cgx, ddy=cpy-cgy;
        float inter_diag = ddx*ddx + ddy*ddy;
        float cltx=fminf(dx1,gx1), clty=fminf(dy1,gy1);
        float crbx=fmaxf(dx2,gx2), crby=fmaxf(dy2,gy2);
        float odx=crbx-cltx, ody=crby-clty;
        float outer_diag = odx*odx + ody*ody;
        float diou = fminf(fmaxf(iou - inter_diag/outer_diag, -1.0f), 1.0f);
        locv += 1.0f - diou;
      }
    }
    *(float4*)(conf_neg + bp0) = make_float4(cn[0],cn[1],cn[2],cn[3]);
  }
  __shared__ float sl[256]; __shared__ float scf[256]; __shared__ int sp[256];
  sl[t]=locv; scf[t]=confpv; sp[t]=posv;
  __syncthreads();
  for (int st=128; st>0; st>>=1){
    if (t<st){ sl[t]+=sl[t+st]; scf[t]+=scf[t+st]; sp[t]+=sp[t+st]; }
    __syncthreads();
  }
  if (t==0){
    if (sl[0]  != 0.0f) atomicAdd(&acc[1], (double)sl[0]);
    if (scf[0] != 0.0f) atomicAdd(&acc[2], (double)scf[0]);
    if (sp[0]  != 0)    atomicAdd(&n_pos[b], sp[0]);
  }
}

// ---- phase E (parallel radix-select, 3 rounds of 12/12/8 bits) ----
template<int ROUND>
__global__ void histE_kernel(const float* __restrict__ conf_neg,
                             const int* __restrict__ n_pos,
                             const unsigned* __restrict__ prefix,
                             unsigned* __restrict__ hist){
  int b = blockIdx.y, c = blockIdx.x, t = threadIdx.x;
  if (n_pos[b] <= 0) return;
  const int nb = (ROUND==2)?256:4096;
  __shared__ unsigned h[4096];
  for (int i=t;i<nb;i+=256) h[i]=0u;
  __syncthreads();
  unsigned pref = (ROUND==0)?0u:prefix[b];
  const float* cn = conf_neg + (size_t)b*Pn;
  int p0 = c*CHUNK, p1 = min(Pn, p0+CHUNK);
  for (int p=p0+t; p<p1; p+=256){
    unsigned key = __float_as_uint(cn[p]);
    if (ROUND==0){
      atomicAdd(&h[key>>20],1u);
    } else if (ROUND==1){
      if ((key>>20)==(pref>>20)) atomicAdd(&h[(key>>8)&0xFFFu],1u);
    } else {
      if ((key>>8)==(pref>>8)) atomicAdd(&h[key&0xFFu],1u);
    }
  }
  __syncthreads();
  unsigned* gh = hist + (size_t)b*4096;
  for (int i=t;i<nb;i+=256) if (h[i]) atomicAdd(&gh[i], h[i]);
}

template<int ROUND>
__global__ void scanE_kernel(const unsigned* __restrict__ hist,
                             const int* __restrict__ n_pos,
                             unsigned* __restrict__ prefix,
                             int* __restrict__ krem_st){
  int b = blockIdx.x, t = threadIdx.x;
  int K = 2*n_pos[b];
  if (K <= 0) return;
  const int nb = (ROUND==2)?256:4096;
  const int per = nb/256;
  const unsigned* gh = hist + (size_t)b*4096;
  unsigned cnt[per>0?per:1];
  unsigned ts = 0;
  #pragma unroll
  for (int i=0;i<per;i++){ cnt[i]=gh[t*per+i]; ts+=cnt[i]; }
  __shared__ unsigned sh[256];
  sh[t]=ts;
  __syncthreads();
  for (int off=1; off<256; off<<=1){
    unsigned v = (t+off<256)? sh[t+off]:0u;   // read (after barrier)
    __syncthreads();
    sh[t]+=v;                                  // write
    __syncthreads();
  }
  int krem = (ROUND==0)? K : krem_st[b];
  unsigned incl = sh[t];           // count of keys in bins >= this thread's lowest
  unsigned above = incl - ts;      // count in strictly-higher threads' bins
  if ((int)above < krem && krem <= (int)incl){
    int acc = (int)above;
    #pragma unroll
    for (int i=per-1;i>=0;i--){
      acc += (int)cnt[i];
      if (acc >= krem){
        unsigned sel = (unsigned)(t*per+i);
        int krem_new = krem - (acc - (int)cnt[i]);
        if (ROUND==0)      prefix[b]  = sel<<20;
        else if (ROUND==1) prefix[b] |= sel<<8;
        else               prefix[b] |= sel;
        krem_st[b]=krem_new;
        break;
      }
    }
  }
}

// Final: sum = sum(v > t) + krem * t  (exact "first K of descending sort")
__global__ void finalE_kernel(const float* __restrict__ conf_neg,
                              const int* __restrict__ n_pos,
                              const unsigned* __restrict__ prefix,
                              const int* __restrict__ krem_st,
                              double* __restrict__ acc){
  int b = blockIdx.y, c = blockIdx.x, t = threadIdx.x;
  int K = 2*n_pos[b];
  if (K <= 0) return;
  const float* cn = conf_neg + (size_t)b*Pn;
  int p0=c*CHUNK, p1=min(Pn,p0+CHUNK);
  float s=0.0f;
  if (K >= Pn){
    for (int p=p0+t;p<p1;p+=256) s += cn[p];
  } else {
    unsigned tb = prefix[b];
    for (int p=p0+t;p<p1;p+=256){
      float v = cn[p];
      if (__float_as_uint(v) > tb) s += v;
    }
  }
  __shared__ float sr[256];
  sr[t]=s; __syncthreads();
  for (int st=128;st>0;st>>=1){ if(t<st) sr[t]+=sr[t+st]; __syncthreads(); }
  if (t==0){
    double add = (double)sr[0];
    if (c==0 && K < Pn) add += (double)krem_st[b] * (double)__uint_as_float(prefix[b]);
    if (add != 0.0) atomicAdd(&acc[3], add);
  }
}

// ---- final combine ----
__global__ void final_kernel(const int* __restrict__ n_pos,
                             const double* __restrict__ acc,
                             float* __restrict__ out){
  if (threadIdx.x==0 && blockIdx.x==0){
    int tp = 0;
    for (int b=0;b<Bn;b++) tp += n_pos[b];
    float total = (float)tp;
    float conf_loss = (float)(acc[3] + acc[2]) / total;
    float loc_loss  = (float)acc[1] / total;
    float seg_loss  = -(float)acc[0];
    out[0] = conf_loss + loc_loss + seg_loss;
  }
}

extern "C" void kernel_launch(void* const* d_in, const int* in_sizes, int n_in,
                              void* d_out, int out_size, void* d_ws, size_t ws_size,
                              hipStream_t stream) {
  const float* odm_locs   = (const float*)d_in[0];
  const float* odm_scores = (const float*)d_in[1];
  const float* att        = (const float*)d_in[2];
  const float* boxes      = (const float*)d_in[3];
  const int*   labels     = (const int*)d_in[4];
  const float* ign        = (const float*)d_in[5];
  const float* priors     = (const float*)d_in[6];
  float* out = (float*)d_out;

  size_t np = (size_t)Bn * Pn;
  float* ov_prior  = (float*)d_ws;                 // B*P f32
  int*   objinfo   = (int*)(ov_prior + np);        // B*P i32 (bits0-7 obj, bit8 ignored)
  float* conf_neg  = (float*)(objinfo + np);       // B*P f32
  unsigned long long* key_obj = (unsigned long long*)(conf_neg + np); // B*O u64
  int*   n_pos     = (int*)(key_obj + (size_t)Bn*On); // B i32
  double* acc      = (double*)(n_pos + Bn);        // [seg, loc, conf_pos, conf_hard]

  // radix-select scratch lives in the ov_prior region (dead after phaseD):
  unsigned* histB  = (unsigned*)ov_prior;
  unsigned* prefix = histB + 3*(size_t)Bn*4096;
  int*      krem   = (int*)(prefix + Bn);

  // zero key_obj + n_pos + acc in one contiguous memset
  hipMemsetAsync(key_obj, 0, (size_t)Bn*On*8 + Bn*sizeof(int) + 4*sizeof(double), stream);

  int pblocks = (Pn + 255) / 256;
  int dblocks = (Pn/4 + 255) / 256;
  seg_kernel  <<<(ATT_N+255)/256, 256, 0, stream>>>(att, acc);
  phaseA_kernel<<<dim3(pblocks, Bn), 256, 0, stream>>>(boxes, ign, priors, ov_prior, objinfo);
  phaseB_kernel<<<dim3(PCn, On/OC, Bn), 256, 0, stream>>>(boxes, priors, key_obj);
  phaseC_kernel<<<1, 64, 0, stream>>>(key_obj, ov_prior, objinfo);
  phaseD_kernel<<<dim3(dblocks, Bn), 256, 0, stream>>>(odm_locs, odm_scores, boxes, labels,
                                                       priors, ov_prior, objinfo,
                                                       conf_neg, n_pos, acc);
  // ov_prior is dead from here; reuse as radix scratch.
  hipMemsetAsync(histB, 0, 3*(size_t)Bn*4096*sizeof(unsigned), stream);
  histE_kernel<0><<<dim3(CHn, Bn), 256, 0, stream>>>(conf_neg, n_pos, prefix, histB);
  scanE_kernel<0><<<Bn, 256, 0, stream>>>(histB, n_pos, prefix, krem);
  histE_kernel<1><<<dim3(CHn, Bn), 256, 0, stream>>>(conf_neg, n_pos, prefix, histB + (size_t)Bn*4096);
  scanE_kernel<1><<<Bn, 256, 0, stream>>>(histB + (size_t)Bn*4096, n_pos, prefix, krem);
  histE_kernel<2><<<dim3(CHn, Bn), 256, 0, stream>>>(conf_neg, n_pos, prefix, histB + 2*(size_t)Bn*4096);
  scanE_kernel<2><<<Bn, 256, 0, stream>>>(histB + 2*(size_t)Bn*4096, n_pos, prefix, krem);
  finalE_kernel<<<dim3(CHn, Bn), 256, 0, stream>>>(conf_neg, n_pos, prefix, krem, acc);
  final_kernel<<<1, 64, 0, stream>>>(n_pos, acc, out);
}

// Round 12
// 237.970 us; speedup vs baseline: 1.6028x; 1.0031x over previous
//
#include <hip/hip_runtime.h>
#include <math.h>

#define Bn 32
#define Pn 42840
#define On 64
#define NIn 8
#define Cn 11
#define ATT_N (32*56*96)
#define THRESHOLD_F 0.4f
#define THETA_F 0.1f
#define CHn 16
#define CHUNK ((Pn + CHn - 1)/CHn)
#define OC 8            /* objects per phaseB block */
#define PCn 8           /* prior chunks; Pn = 8*5355 exactly */
#define PCH (Pn/PCn)

// keep a float4 live in VGPRs at this program point (defeats load sinking)
#define KEEPF4(v) asm volatile("" :: "v"((v).x), "v"((v).y), "v"((v).z), "v"((v).w))

// ---- seg loss: sum of max(log1p(-a), -100); negated at the end ----
__global__ void seg_kernel(const float* __restrict__ att, double* __restrict__ acc){
  int i = blockIdx.x*256 + threadIdx.x;
  float v = 0.0f;
  if (i < ATT_N) v = fmaxf(log1pf(-att[i]), -100.0f);
  __shared__ float s[256];
  int t = threadIdx.x;
  s[t]=v; __syncthreads();
  for (int st=128; st>0; st>>=1){ if (t<st) s[t]+=s[t+st]; __syncthreads(); }
  if (t==0) atomicAdd(&acc[0], (double)s[0]);
}

// ---- phase A: per (b,p) argmax over objects via cross-mult; 2 divisions total ----
__global__ void phaseA_kernel(const float* __restrict__ boxes,
                              const float* __restrict__ ign,
                              const float* __restrict__ priors,
                              float* __restrict__ ov_prior,
                              int* __restrict__ objinfo){
  __shared__ float sb[On*4];
  __shared__ float si[NIn*4];
  __shared__ float sa[On];
  __shared__ float sia[NIn];
  int b = blockIdx.y;
  int t = threadIdx.x;
  if (t < On*4)  sb[t] = boxes[(size_t)b*On*4 + t];
  if (t < NIn*4) si[t] = ign[(size_t)b*NIn*4 + t];
  __syncthreads();
  if (t < On)  sa[t]  = (sb[4*t+2]-sb[4*t])*(sb[4*t+3]-sb[4*t+1]);
  if (t < NIn) sia[t] = (si[4*t+2]-si[4*t])*(si[4*t+3]-si[4*t+1]);
  __syncthreads();
  int p = blockIdx.x*256 + t;
  if (p >= Pn) return;
  float4 pc = ((const float4*)priors)[p];
  float px1 = pc.x - pc.z/2.0f, py1 = pc.y - pc.w/2.0f;
  float px2 = pc.x + pc.z/2.0f, py2 = pc.y + pc.w/2.0f;
  float ab = (px2-px1)*(py2-py1);
  // argmax over objects: track (inter, union) winner via cross-multiplied compare
  float bi = -1.0f, bu = 1.0f; int bo = 0;
  #pragma unroll 4
  for (int o=0;o<On;o++){
    float ltx=fmaxf(sb[4*o],px1),   lty=fmaxf(sb[4*o+1],py1);
    float rbx=fminf(sb[4*o+2],px2), rby=fminf(sb[4*o+3],py2);
    float w=fmaxf(rbx-ltx,0.0f), h=fmaxf(rby-lty,0.0f);
    float inter=w*h;
    float uni=(sa[o]+ab)-inter;
    if (inter*bu > bi*uni){ bi=inter; bu=uni; bo=o; }  // strict > keeps first
  }
  float ii = -1.0f, iu = 1.0f;
  #pragma unroll
  for (int o=0;o<NIn;o++){
    float ltx=fmaxf(si[4*o],px1),   lty=fmaxf(si[4*o+1],py1);
    float rbx=fminf(si[4*o+2],px2), rby=fminf(si[4*o+3],py2);
    float w=fmaxf(rbx-ltx,0.0f), h=fmaxf(rby-lty,0.0f);
    float inter=w*h;
    float uni=(sia[o]+ab)-inter;
    if (inter*iu > ii*uni){ ii=inter; iu=iu=uni; }
  }
  float best = bi/bu;        // one exact division
  float ig   = ii/iu;        // one exact division
  size_t bp = (size_t)b*Pn + p;
  ov_prior[bp] = best;
  objinfo[bp]  = bo | ((ig >= THETA_F) ? 256 : 0);
}

// ---- phase B: per (b,o) argmax over P; 8 objects/block, cross-mult inner loop,
//      one division per (thread,object), u64 key wave-reduce + global atomicMax ----
__global__ void phaseB_kernel(const float* __restrict__ boxes,
                              const float* __restrict__ priors,
                              unsigned long long* __restrict__ key_obj){
  int c = blockIdx.x, og = blockIdx.y, b = blockIdx.z, t = threadIdx.x;
  float ox1[OC], oy1[OC], ox2[OC], oy2[OC], oa[OC];
  const float4* bx = (const float4*)(boxes + ((size_t)b*On + og*OC)*4);
  #pragma unroll
  for (int j=0;j<OC;j++){
    float4 v = bx[j];
    ox1[j]=v.x; oy1[j]=v.y; ox2[j]=v.z; oy2[j]=v.w;
    oa[j]=(v.z-v.x)*(v.w-v.y);
  }
  float bi[OC], bu[OC]; unsigned bp_[OC];
  #pragma unroll
  for (int j=0;j<OC;j++){ bi[j]=-1.0f; bu[j]=1.0f; bp_[j]=0u; }
  int p0 = c*PCH;
  for (int p=p0+t; p<p0+PCH; p+=256){      // PCH divides evenly; all lanes iterate
    float4 pc = ((const float4*)priors)[p];
    float px1 = pc.x - pc.z/2.0f, py1 = pc.y - pc.w/2.0f;
    float px2 = pc.x + pc.z/2.0f, py2 = pc.y + pc.w/2.0f;
    float ab = (px2-px1)*(py2-py1);
    #pragma unroll
    for (int j=0;j<OC;j++){
      float ltx=fmaxf(ox1[j],px1), lty=fmaxf(oy1[j],py1);
      float rbx=fminf(ox2[j],px2), rby=fminf(oy2[j],py2);
      float w=fmaxf(rbx-ltx,0.0f), h=fmaxf(rby-lty,0.0f);
      float inter=w*h;
      float uni=(oa[j]+ab)-inter;
      if (inter*bu[j] > bi[j]*uni){ bi[j]=inter; bu[j]=uni; bp_[j]=(unsigned)p; }
    }
  }
  #pragma unroll
  for (int j=0;j<OC;j++){
    float iou = bi[j]/bu[j];               // one exact division per object
    unsigned long long key = ((unsigned long long)__float_as_uint(iou)<<32)
                           | (unsigned long long)(0xFFFFFFFFu - bp_[j]);
    #pragma unroll
    for (int d=32; d>0; d>>=1){
      unsigned long long o2 = __shfl_xor(key, d, 64);
      if (o2 > key) key = o2;
    }
    if ((t & 63) == 0)
      atomicMax(&key_obj[(size_t)b*On + og*OC + j], key);
  }
}

// ---- phase C: sequential per-batch scatter (set 1.0; last-write-wins rank) ----
__global__ void phaseC_kernel(const unsigned long long* __restrict__ key_obj,
                              float* __restrict__ ov_prior,
                              int* __restrict__ objinfo){
  int b = threadIdx.x;
  if (b >= Bn) return;
  int rank = -1;
  for (int o=0;o<On;o++){
    unsigned long long k = key_obj[(size_t)b*On+o];
    if ((unsigned)(k>>32) > 0u){            // iou > 0  <=> valid
      rank++;                               // jranks = cumsum(valid)-1
      int p = (int)(0xFFFFFFFFu - (unsigned)(k & 0xFFFFFFFFu));
      size_t bp = (size_t)b*Pn + p;
      ov_prior[bp] = 1.0f;
      objinfo[bp] = (objinfo[bp] & 256) | rank; // ascending o => overwrite == max(jr)
    }
  }
}

// ---- phase D: 4 priors/thread, loads pinned live (no sinking), all-register scores ----
__global__ void __launch_bounds__(256, 4)
phaseD_kernel(const float* __restrict__ odm_locs,
              const float* __restrict__ odm_scores,
              const float* __restrict__ boxes,
              const int* __restrict__ labels,
              const float* __restrict__ priors,
              const float* __restrict__ ov_prior,
              const int* __restrict__ objinfo,
              float* __restrict__ conf_neg,
              int* __restrict__ n_pos,
              double* __restrict__ acc){
  int b = blockIdx.y;
  int t = threadIdx.x;
  int p0 = (blockIdx.x*256 + t)*4;
  float locv = 0.0f, confpv = 0.0f; int posv = 0;
  if (p0 < Pn){                           // Pn%4==0 -> all 4 priors valid
    size_t bp0 = (size_t)b*Pn + p0;
    float4 sc4[11];
    const float4* src = (const float4*)(odm_scores + bp0*Cn);  // 16B-aligned
    #pragma unroll
    for (int i=0;i<11;i++) sc4[i] = src[i];
    int4   info4 = *(const int4*)(objinfo + bp0);
    float4 ovp4  = *(const float4*)(ov_prior + bp0);
    // pin all loads live here: forces the 13 loads to issue back-to-back
    #pragma unroll
    for (int i=0;i<11;i++) KEEPF4(sc4[i]);
    const float* sc = (const float*)sc4;   // constant indices only (post-unroll)
    float cn[4];
    #pragma unroll
    for (int j=0;j<4;j++){
      int info = (&info4.x)[j];
      int obj = info & 0xFF;
      bool ignored = (info & 256) != 0;
      int label = labels[b*On + obj];
      if ((&ovp4.x)[j] < THRESHOLD_F) label = 0;
      bool pos = label > 0;
      float m = sc[j*Cn];
      #pragma unroll
      for (int c=1;c<Cn;c++) m = fmaxf(m, sc[j*Cn+c]);
      float se = 0.0f, slab = 0.0f;
      #pragma unroll
      for (int c=0;c<Cn;c++){
        float v = sc[j*Cn+c];
        se += expf(v-m);
        if (c == label) slab = v;          // c is compile-time -> cndmask chain
      }
      float conf = logf(se) - (slab-m);
      cn[j] = (pos || ignored) ? 0.0f : conf;
      if (pos){
        posv += 1; confpv += conf;
        size_t bp = bp0 + j;
        float4 pc = ((const float4*)priors)[p0+j];
        float4 g  = ((const float4*)odm_locs)[bp];
        float cx = g.x*pc.z/10.0f + pc.x;
        float cy = g.y*pc.w/10.0f + pc.y;
        float w  = expf(g.z/5.0f)*pc.z;
        float h  = expf(g.w/5.0f)*pc.w;
        float dx1 = cx - w/2.0f, dy1 = cy - h/2.0f;
        float dx2 = cx + w/2.0f, dy2 = cy + h/2.0f;
        const float* gt = boxes + ((size_t)b*On + obj)*4;
        float gx1=gt[0], gy1=gt[1], gx2=gt[2], gy2=gt[3];
        float ltx=fmaxf(dx1,gx1), lty=fmaxf(dy1,gy1);
        float rbx=fminf(dx2,gx2), rby=fminf(dy2,gy2);
        float iw=fmaxf(rbx-ltx,0.0f), ih=fmaxf(rby-lty,0.0f);
        float inter=iw*ih;
        float ap=(dx2-dx1)*(dy2-dy1);
        float ag=(gx2-gx1)*(gy2-gy1);
        float iou = inter/((ap+ag)-inter);
        float cpx=(dx1+dx2)/2.0f, cpy=(dy1+dy2)/2.0f;
        float cgx=(gx1+gx2)/2.0f, cgy=(gy1+gy2)/2.0f;
        float ddx=cpx-cgx, ddy=cpy-cgy;
        float inter_diag = ddx*ddx + ddy*ddy;
        float cltx=fminf(dx1,gx1), clty=fminf(dy1,gy1);
        float crbx=fmaxf(dx2,gx2), crby=fmaxf(dy2,gy2);
        float odx=crbx-cltx, ody=crby-clty;
        float outer_diag = odx*odx + ody*ody;
        float diou = fminf(fmaxf(iou - inter_diag/outer_diag, -1.0f), 1.0f);
        locv += 1.0f - diou;
      }
    }
    *(float4*)(conf_neg + bp0) = make_float4(cn[0],cn[1],cn[2],cn[3]);
  }
  __shared__ float sl[256]; __shared__ float scf[256]; __shared__ int sp[256];
  sl[t]=locv; scf[t]=confpv; sp[t]=posv;
  __syncthreads();
  for (int st=128; st>0; st>>=1){
    if (t<st){ sl[t]+=sl[t+st]; scf[t]+=scf[t+st]; sp[t]+=sp[t+st]; }
    __syncthreads();
  }
  if (t==0){
    if (sl[0]  != 0.0f) atomicAdd(&acc[1], (double)sl[0]);
    if (scf[0] != 0.0f) atomicAdd(&acc[2], (double)scf[0]);
    if (sp[0]  != 0)    atomicAdd(&n_pos[b], sp[0]);
  }
}

// ---- phase E (parallel radix-select, 3 rounds of 12/12/8 bits) ----
template<int ROUND>
__global__ void histE_kernel(const float* __restrict__ conf_neg,
                             const int* __restrict__ n_pos,
                             const unsigned* __restrict__ prefix,
                             unsigned* __restrict__ hist){
  int b = blockIdx.y, c = blockIdx.x, t = threadIdx.x;
  if (n_pos[b] <= 0) return;
  const int nb = (ROUND==2)?256:4096;
  __shared__ unsigned h[4096];
  for (int i=t;i<nb;i+=256) h[i]=0u;
  __syncthreads();
  unsigned pref = (ROUND==0)?0u:prefix[b];
  const float* cn = conf_neg + (size_t)b*Pn;
  int p0 = c*CHUNK, p1 = min(Pn, p0+CHUNK);
  for (int p=p0+t; p<p1; p+=256){
    unsigned key = __float_as_uint(cn[p]);
    if (ROUND==0){
      atomicAdd(&h[key>>20],1u);
    } else if (ROUND==1){
      if ((key>>20)==(pref>>20)) atomicAdd(&h[(key>>8)&0xFFFu],1u);
    } else {
      if ((key>>8)==(pref>>8)) atomicAdd(&h[key&0xFFu],1u);
    }
  }
  __syncthreads();
  unsigned* gh = hist + (size_t)b*4096;
  for (int i=t;i<nb;i+=256) if (h[i]) atomicAdd(&gh[i], h[i]);
}

template<int ROUND>
__global__ void scanE_kernel(const unsigned* __restrict__ hist,
                             const int* __restrict__ n_pos,
                             unsigned* __restrict__ prefix,
                             int* __restrict__ krem_st){
  int b = blockIdx.x, t = threadIdx.x;
  int K = 2*n_pos[b];
  if (K <= 0) return;
  const int nb = (ROUND==2)?256:4096;
  const int per = nb/256;
  const unsigned* gh = hist + (size_t)b*4096;
  unsigned cnt[per>0?per:1];
  unsigned ts = 0;
  #pragma unroll
  for (int i=0;i<per;i++){ cnt[i]=gh[t*per+i]; ts+=cnt[i]; }
  __shared__ unsigned sh[256];
  sh[t]=ts;
  __syncthreads();
  for (int off=1; off<256; off<<=1){
    unsigned v = (t+off<256)? sh[t+off]:0u;   // read (after barrier)
    __syncthreads();
    sh[t]+=v;                                  // write
    __syncthreads();
  }
  int krem = (ROUND==0)? K : krem_st[b];
  unsigned incl = sh[t];           // count of keys in bins >= this thread's lowest
  unsigned above = incl - ts;      // count in strictly-higher threads' bins
  if ((int)above < krem && krem <= (int)incl){
    int acc = (int)above;
    #pragma unroll
    for (int i=per-1;i>=0;i--){
      acc += (int)cnt[i];
      if (acc >= krem){
        unsigned sel = (unsigned)(t*per+i);
        int krem_new = krem - (acc - (int)cnt[i]);
        if (ROUND==0)      prefix[b]  = sel<<20;
        else if (ROUND==1) prefix[b] |= sel<<8;
        else               prefix[b] |= sel;
        krem_st[b]=krem_new;
        break;
      }
    }
  }
}

// Final: sum = sum(v > t) + krem * t  (exact "first K of descending sort")
__global__ void finalE_kernel(const float* __restrict__ conf_neg,
                              const int* __restrict__ n_pos,
                              const unsigned* __restrict__ prefix,
                              const int* __restrict__ krem_st,
                              double* __restrict__ acc){
  int b = blockIdx.y, c = blockIdx.x, t = threadIdx.x;
  int K = 2*n_pos[b];
  if (K <= 0) return;
  const float* cn = conf_neg + (size_t)b*Pn;
  int p0=c*CHUNK, p1=min(Pn,p0+CHUNK);
  float s=0.0f;
  if (K >= Pn){
    for (int p=p0+t;p<p1;p+=256) s += cn[p];
  } else {
    unsigned tb = prefix[b];
    for (int p=p0+t;p<p1;p+=256){
      float v = cn[p];
      if (__float_as_uint(v) > tb) s += v;
    }
  }
  __shared__ float sr[256];
  sr[t]=s; __syncthreads();
  for (int st=128;st>0;st>>=1){ if(t<st) sr[t]+=sr[t+st]; __syncthreads(); }
  if (t==0){
    double add = (double)sr[0];
    if (c==0 && K < Pn) add += (double)krem_st[b] * (double)__uint_as_float(prefix[b]);
    if (add != 0.0) atomicAdd(&acc[3], add);
  }
}

// ---- final combine ----
__global__ void final_kernel(const int* __restrict__ n_pos,
                             const double* __restrict__ acc,
                             float* __restrict__ out){
  if (threadIdx.x==0 && blockIdx.x==0){
    int tp = 0;
    for (int b=0;b<Bn;b++) tp += n_pos[b];
    float total = (float)tp;
    float conf_loss = (float)(acc[3] + acc[2]) / total;
    float loc_loss  = (float)acc[1] / total;
    float seg_loss  = -(float)acc[0];
    out[0] = conf_loss + loc_loss + seg_loss;
  }
}

extern "C" void kernel_launch(void* const* d_in, const int* in_sizes, int n_in,
                              void* d_out, int out_size, void* d_ws, size_t ws_size,
                              hipStream_t stream) {
  const float* odm_locs   = (const float*)d_in[0];
  const float* odm_scores = (const float*)d_in[1];
  const float* att        = (const float*)d_in[2];
  const float* boxes      = (const float*)d_in[3];
  const int*   labels     = (const int*)d_in[4];
  const float* ign        = (const float*)d_in[5];
  const float* priors     = (const float*)d_in[6];
  float* out = (float*)d_out;

  size_t np = (size_t)Bn * Pn;
  float* ov_prior  = (float*)d_ws;                 // B*P f32
  int*   objinfo   = (int*)(ov_prior + np);        // B*P i32 (bits0-7 obj, bit8 ignored)
  float* conf_neg  = (float*)(objinfo + np);       // B*P f32
  unsigned long long* key_obj = (unsigned long long*)(conf_neg + np); // B*O u64
  int*   n_pos     = (int*)(key_obj + (size_t)Bn*On); // B i32
  double* acc      = (double*)(n_pos + Bn);        // [seg, loc, conf_pos, conf_hard]

  // radix-select scratch lives in the ov_prior region (dead after phaseD):
  unsigned* histB  = (unsigned*)ov_prior;
  unsigned* prefix = histB + 3*(size_t)Bn*4096;
  int*      krem   = (int*)(prefix + Bn);

  // zero key_obj + n_pos + acc in one contiguous memset
  hipMemsetAsync(key_obj, 0, (size_t)Bn*On*8 + Bn*sizeof(int) + 4*sizeof(double), stream);

  int pblocks = (Pn + 255) / 256;
  int dblocks = (Pn/4 + 255) / 256;
  seg_kernel  <<<(ATT_N+255)/256, 256, 0, stream>>>(att, acc);
  phaseA_kernel<<<dim3(pblocks, Bn), 256, 0, stream>>>(boxes, ign, priors, ov_prior, objinfo);
  phaseB_kernel<<<dim3(PCn, On/OC, Bn), 256, 0, stream>>>(boxes, priors, key_obj);
  phaseC_kernel<<<1, 64, 0, stream>>>(key_obj, ov_prior, objinfo);
  phaseD_kernel<<<dim3(dblocks, Bn), 256, 0, stream>>>(odm_locs, odm_scores, boxes, labels,
                                                       priors, ov_prior, objinfo,
                                                       conf_neg, n_pos, acc);
  // ov_prior is dead from here; reuse as radix scratch.
  hipMemsetAsync(histB, 0, 3*(size_t)Bn*4096*sizeof(unsigned), stream);
  histE_kernel<0><<<dim3(CHn, Bn), 256, 0, stream>>>(conf_neg, n_pos, prefix, histB);
  scanE_kernel<0><<<Bn, 256, 0, stream>>>(histB, n_pos, prefix, krem);
  histE_kernel<1><<<dim3(CHn, Bn), 256, 0, stream>>>(conf_neg, n_pos, prefix, histB + (size_t)Bn*4096);
  scanE_kernel<1><<<Bn, 256, 0, stream>>>(histB + (size_t)Bn*4096, n_pos, prefix, krem);
  histE_kernel<2><<<dim3(CHn, Bn), 256, 0, stream>>>(conf_neg, n_pos, prefix, histB + 2*(size_t)Bn*4096);
  scanE_kernel<2><<<Bn, 256, 0, stream>>>(histB + 2*(size_t)Bn*4096, n_pos, prefix, krem);
  finalE_kernel<<<dim3(CHn, Bn), 256, 0, stream>>>(conf_neg, n_pos, prefix, krem, acc);
  final_kernel<<<1, 64, 0, stream>>>(n_pos, acc, out);
}

// Round 13
// 216.271 us; speedup vs baseline: 1.7636x; 1.1003x over previous
//
#include <hip/hip_runtime.h>
#include <math.h>

#define Bn 32
#define Pn 42840
#define On 64
#define NIn 8
#define Cn 11
#define ATT_N (32*56*96)
#define THRESHOLD_F 0.4f
#define THETA_F 0.1f
#define CHn 16
#define CHUNK ((Pn + CHn - 1)/CHn)
#define OC 8            /* objects per phaseB block */
#define PCn 8           /* prior chunks; Pn = 8*5355 exactly */
#define PCH (Pn/PCn)
#define DBLK 42         /* phaseD blocks per batch: ceil(Pn/4/256) */
#define WPB  (DBLK*4)   /* phaseD waves per batch = 168 */
#define SEGB ((ATT_N+255)/256)   /* 672 seg blocks */

// ---- seg loss: per-block partial (no atomics) ----
__global__ void seg_kernel(const float* __restrict__ att, float* __restrict__ pseg){
  int i = blockIdx.x*256 + threadIdx.x;
  float v = 0.0f;
  if (i < ATT_N) v = fmaxf(log1pf(-att[i]), -100.0f);
  __shared__ float s[256];
  int t = threadIdx.x;
  s[t]=v; __syncthreads();
  for (int st=128; st>0; st>>=1){ if (t<st) s[t]+=s[t+st]; __syncthreads(); }
  if (t==0) pseg[blockIdx.x] = s[0];
}

// ---- phase A: per (b,p) argmax over objects via cross-mult; 2 divisions total ----
__global__ void phaseA_kernel(const float* __restrict__ boxes,
                              const float* __restrict__ ign,
                              const float* __restrict__ priors,
                              float* __restrict__ ov_prior,
                              int* __restrict__ objinfo){
  __shared__ float sb[On*4];
  __shared__ float si[NIn*4];
  __shared__ float sa[On];
  __shared__ float sia[NIn];
  int b = blockIdx.y;
  int t = threadIdx.x;
  if (t < On*4)  sb[t] = boxes[(size_t)b*On*4 + t];
  if (t < NIn*4) si[t] = ign[(size_t)b*NIn*4 + t];
  __syncthreads();
  if (t < On)  sa[t]  = (sb[4*t+2]-sb[4*t])*(sb[4*t+3]-sb[4*t+1]);
  if (t < NIn) sia[t] = (si[4*t+2]-si[4*t])*(si[4*t+3]-si[4*t+1]);
  __syncthreads();
  int p = blockIdx.x*256 + t;
  if (p >= Pn) return;
  float4 pc = ((const float4*)priors)[p];
  float px1 = pc.x - pc.z/2.0f, py1 = pc.y - pc.w/2.0f;
  float px2 = pc.x + pc.z/2.0f, py2 = pc.y + pc.w/2.0f;
  float ab = (px2-px1)*(py2-py1);
  float bi = -1.0f, bu = 1.0f; int bo = 0;
  #pragma unroll 4
  for (int o=0;o<On;o++){
    float ltx=fmaxf(sb[4*o],px1),   lty=fmaxf(sb[4*o+1],py1);
    float rbx=fminf(sb[4*o+2],px2), rby=fminf(sb[4*o+3],py2);
    float w=fmaxf(rbx-ltx,0.0f), h=fmaxf(rby-lty,0.0f);
    float inter=w*h;
    float uni=(sa[o]+ab)-inter;
    if (inter*bu > bi*uni){ bi=inter; bu=uni; bo=o; }  // strict > keeps first
  }
  float ii = -1.0f, iu = 1.0f;
  #pragma unroll
  for (int o=0;o<NIn;o++){
    float ltx=fmaxf(si[4*o],px1),   lty=fmaxf(si[4*o+1],py1);
    float rbx=fminf(si[4*o+2],px2), rby=fminf(si[4*o+3],py2);
    float w=fmaxf(rbx-ltx,0.0f), h=fmaxf(rby-lty,0.0f);
    float inter=w*h;
    float uni=(sia[o]+ab)-inter;
    if (inter*iu > ii*uni){ ii=inter; iu=uni; }
  }
  float best = bi/bu;        // one exact division
  float ig   = ii/iu;        // one exact division
  size_t bp = (size_t)b*Pn + p;
  ov_prior[bp] = best;
  objinfo[bp]  = bo | ((ig >= THETA_F) ? 256 : 0);
}

// ---- phase B: per (b,o) argmax over P; cross-mult, u64 key wave-reduce + atomicMax ----
__global__ void phaseB_kernel(const float* __restrict__ boxes,
                              const float* __restrict__ priors,
                              unsigned long long* __restrict__ key_obj){
  int c = blockIdx.x, og = blockIdx.y, b = blockIdx.z, t = threadIdx.x;
  float ox1[OC], oy1[OC], ox2[OC], oy2[OC], oa[OC];
  const float4* bx = (const float4*)(boxes + ((size_t)b*On + og*OC)*4);
  #pragma unroll
  for (int j=0;j<OC;j++){
    float4 v = bx[j];
    ox1[j]=v.x; oy1[j]=v.y; ox2[j]=v.z; oy2[j]=v.w;
    oa[j]=(v.z-v.x)*(v.w-v.y);
  }
  float bi[OC], bu[OC]; unsigned bp_[OC];
  #pragma unroll
  for (int j=0;j<OC;j++){ bi[j]=-1.0f; bu[j]=1.0f; bp_[j]=0u; }
  int p0 = c*PCH;
  for (int p=p0+t; p<p0+PCH; p+=256){
    float4 pc = ((const float4*)priors)[p];
    float px1 = pc.x - pc.z/2.0f, py1 = pc.y - pc.w/2.0f;
    float px2 = pc.x + pc.z/2.0f, py2 = pc.y + pc.w/2.0f;
    float ab = (px2-px1)*(py2-py1);
    #pragma unroll
    for (int j=0;j<OC;j++){
      float ltx=fmaxf(ox1[j],px1), lty=fmaxf(oy1[j],py1);
      float rbx=fminf(ox2[j],px2), rby=fminf(oy2[j],py2);
      float w=fmaxf(rbx-ltx,0.0f), h=fmaxf(rby-lty,0.0f);
      float inter=w*h;
      float uni=(oa[j]+ab)-inter;
      if (inter*bu[j] > bi[j]*uni){ bi[j]=inter; bu[j]=uni; bp_[j]=(unsigned)p; }
    }
  }
  #pragma unroll
  for (int j=0;j<OC;j++){
    float iou = bi[j]/bu[j];               // one exact division per object
    unsigned long long key = ((unsigned long long)__float_as_uint(iou)<<32)
                           | (unsigned long long)(0xFFFFFFFFu - bp_[j]);
    #pragma unroll
    for (int d=32; d>0; d>>=1){
      unsigned long long o2 = __shfl_xor(key, d, 64);
      if (o2 > key) key = o2;
    }
    if ((t & 63) == 0)
      atomicMax(&key_obj[(size_t)b*On + og*OC + j], key);
  }
}

// ---- phase C: sequential per-batch scatter (set 1.0; last-write-wins rank) ----
__global__ void phaseC_kernel(const unsigned long long* __restrict__ key_obj,
                              float* __restrict__ ov_prior,
                              int* __restrict__ objinfo){
  int b = threadIdx.x;
  if (b >= Bn) return;
  int rank = -1;
  for (int o=0;o<On;o++){
    unsigned long long k = key_obj[(size_t)b*On+o];
    if ((unsigned)(k>>32) > 0u){            // iou > 0  <=> valid
      rank++;                               // jranks = cumsum(valid)-1
      int p = (int)(0xFFFFFFFFu - (unsigned)(k & 0xFFFFFFFFu));
      size_t bp = (size_t)b*Pn + p;
      ov_prior[bp] = 1.0f;
      objinfo[bp] = (objinfo[bp] & 256) | rank; // ascending o => overwrite == max(jr)
    }
  }
}

// ---- phase D: 4 priors/thread; per-WAVE shuffle reduce; no barriers, no atomics ----
__global__ void __launch_bounds__(256, 4)
phaseD_kernel(const float* __restrict__ odm_locs,
              const float* __restrict__ odm_scores,
              const float* __restrict__ boxes,
              const int* __restrict__ labels,
              const float* __restrict__ priors,
              const float* __restrict__ ov_prior,
              const int* __restrict__ objinfo,
              float* __restrict__ conf_neg,
              float* __restrict__ ploc,
              float* __restrict__ pconf,
              int* __restrict__ ppos){
  int b = blockIdx.y;
  int t = threadIdx.x;
  int p0 = (blockIdx.x*256 + t)*4;
  float locv = 0.0f, confpv = 0.0f; int posv = 0;
  if (p0 < Pn){                           // Pn%4==0 -> all 4 priors valid
    size_t bp0 = (size_t)b*Pn + p0;
    float4 sc4[11];
    const float4* src = (const float4*)(odm_scores + bp0*Cn);  // 16B-aligned
    #pragma unroll
    for (int i=0;i<11;i++) sc4[i] = src[i];
    int4   info4 = *(const int4*)(objinfo + bp0);
    float4 ovp4  = *(const float4*)(ov_prior + bp0);
    const float* sc = (const float*)sc4;   // constant indices only (post-unroll)
    float cn[4];
    #pragma unroll
    for (int j=0;j<4;j++){
      int info = (&info4.x)[j];
      int obj = info & 0xFF;
      bool ignored = (info & 256) != 0;
      int label = labels[b*On + obj];
      if ((&ovp4.x)[j] < THRESHOLD_F) label = 0;
      bool pos = label > 0;
      float m = sc[j*Cn];
      #pragma unroll
      for (int c=1;c<Cn;c++) m = fmaxf(m, sc[j*Cn+c]);
      float se = 0.0f, slab = 0.0f;
      #pragma unroll
      for (int c=0;c<Cn;c++){
        float v = sc[j*Cn+c];
        se += expf(v-m);
        if (c == label) slab = v;          // c is compile-time -> cndmask chain
      }
      float conf = logf(se) - (slab-m);
      cn[j] = (pos || ignored) ? 0.0f : conf;
      if (pos){
        posv += 1; confpv += conf;
        size_t bp = bp0 + j;
        float4 pc = ((const float4*)priors)[p0+j];
        float4 g  = ((const float4*)odm_locs)[bp];
        float cx = g.x*pc.z/10.0f + pc.x;
        float cy = g.y*pc.w/10.0f + pc.y;
        float w  = expf(g.z/5.0f)*pc.z;
        float h  = expf(g.w/5.0f)*pc.w;
        float dx1 = cx - w/2.0f, dy1 = cy - h/2.0f;
        float dx2 = cx + w/2.0f, dy2 = cy + h/2.0f;
        const float* gt = boxes + ((size_t)b*On + obj)*4;
        float gx1=gt[0], gy1=gt[1], gx2=gt[2], gy2=gt[3];
        float ltx=fmaxf(dx1,gx1), lty=fmaxf(dy1,gy1);
        float rbx=fminf(dx2,gx2), rby=fminf(dy2,gy2);
        float iw=fmaxf(rbx-ltx,0.0f), ih=fmaxf(rby-lty,0.0f);
        float inter=iw*ih;
        float ap=(dx2-dx1)*(dy2-dy1);
        float ag=(gx2-gx1)*(gy2-gy1);
        float iou = inter/((ap+ag)-inter);
        float cpx=(dx1+dx2)/2.0f, cpy=(dy1+dy2)/2.0f;
        float cgx=(gx1+gx2)/2.0f, cgy=(gy1+gy2)/2.0f;
        float ddx=cpx-cgx, ddy=cpy-cgy;
        float inter_diag = ddx*ddx + ddy*ddy;
        float cltx=fminf(dx1,gx1), clty=fminf(dy1,gy1);
        float crbx=fmaxf(dx2,gx2), crby=fmaxf(dy2,gy2);
        float odx=crbx-cltx, ody=crby-clty;
        float outer_diag = odx*odx + ody*ody;
        float diou = fminf(fmaxf(iou - inter_diag/outer_diag, -1.0f), 1.0f);
        locv += 1.0f - diou;
      }
    }
    *(float4*)(conf_neg + bp0) = make_float4(cn[0],cn[1],cn[2],cn[3]);
  }
  // per-wave butterfly reduction, lane 0 writes a unique slot -> zero contention
  #pragma unroll
  for (int d=32; d>0; d>>=1){
    locv   += __shfl_xor(locv,   d, 64);
    confpv += __shfl_xor(confpv, d, 64);
    posv   += __shfl_xor(posv,   d, 64);
  }
  if ((t & 63) == 0){
    int widx = b*WPB + (blockIdx.x<<2) + (t>>6);
    ploc[widx]  = locv;
    pconf[widx] = confpv;
    ppos[widx]  = posv;
  }
}

// ---- n_pos reduce: one block; thread b sums its batch's wave partials ----
__global__ void npos_kernel(const int* __restrict__ ppos, int* __restrict__ n_pos){
  int b = threadIdx.x;
  if (b >= Bn) return;
  int s = 0;
  for (int w=0; w<WPB; w++) s += ppos[b*WPB + w];
  n_pos[b] = s;
}

// ---- phase E (parallel radix-select, 3 rounds of 12/12/8 bits) ----
template<int ROUND>
__global__ void histE_kernel(const float* __restrict__ conf_neg,
                             const int* __restrict__ n_pos,
                             const unsigned* __restrict__ prefix,
                             unsigned* __restrict__ hist){
  int b = blockIdx.y, c = blockIdx.x, t = threadIdx.x;
  if (n_pos[b] <= 0) return;
  const int nb = (ROUND==2)?256:4096;
  __shared__ unsigned h[4096];
  for (int i=t;i<nb;i+=256) h[i]=0u;
  __syncthreads();
  unsigned pref = (ROUND==0)?0u:prefix[b];
  const float* cn = conf_neg + (size_t)b*Pn;
  int p0 = c*CHUNK, p1 = min(Pn, p0+CHUNK);
  for (int p=p0+t; p<p1; p+=256){
    unsigned key = __float_as_uint(cn[p]);
    if (ROUND==0){
      atomicAdd(&h[key>>20],1u);
    } else if (ROUND==1){
      if ((key>>20)==(pref>>20)) atomicAdd(&h[(key>>8)&0xFFFu],1u);
    } else {
      if ((key>>8)==(pref>>8)) atomicAdd(&h[key&0xFFu],1u);
    }
  }
  __syncthreads();
  unsigned* gh = hist + (size_t)b*4096;
  for (int i=t;i<nb;i+=256) if (h[i]) atomicAdd(&gh[i], h[i]);
}

template<int ROUND>
__global__ void scanE_kernel(const unsigned* __restrict__ hist,
                             const int* __restrict__ n_pos,
                             unsigned* __restrict__ prefix,
                             int* __restrict__ krem_st){
  int b = blockIdx.x, t = threadIdx.x;
  int K = 2*n_pos[b];
  if (K <= 0) return;
  const int nb = (ROUND==2)?256:4096;
  const int per = nb/256;
  const unsigned* gh = hist + (size_t)b*4096;
  unsigned cnt[per>0?per:1];
  unsigned ts = 0;
  #pragma unroll
  for (int i=0;i<per;i++){ cnt[i]=gh[t*per+i]; ts+=cnt[i]; }
  __shared__ unsigned sh[256];
  sh[t]=ts;
  __syncthreads();
  for (int off=1; off<256; off<<=1){
    unsigned v = (t+off<256)? sh[t+off]:0u;   // read (after barrier)
    __syncthreads();
    sh[t]+=v;                                  // write
    __syncthreads();
  }
  int krem = (ROUND==0)? K : krem_st[b];
  unsigned incl = sh[t];           // count of keys in bins >= this thread's lowest
  unsigned above = incl - ts;      // count in strictly-higher threads' bins
  if ((int)above < krem && krem <= (int)incl){
    int acc = (int)above;
    #pragma unroll
    for (int i=per-1;i>=0;i--){
      acc += (int)cnt[i];
      if (acc >= krem){
        unsigned sel = (unsigned)(t*per+i);
        int krem_new = krem - (acc - (int)cnt[i]);
        if (ROUND==0)      prefix[b]  = sel<<20;
        else if (ROUND==1) prefix[b] |= sel<<8;
        else               prefix[b] |= sel;
        krem_st[b]=krem_new;
        break;
      }
    }
  }
}

// Final select: per-(b,c) partial doubles; always written (no atomics)
__global__ void finalE_kernel(const float* __restrict__ conf_neg,
                              const int* __restrict__ n_pos,
                              const unsigned* __restrict__ prefix,
                              const int* __restrict__ krem_st,
                              double* __restrict__ phard){
  int b = blockIdx.y, c = blockIdx.x, t = threadIdx.x;
  int K = 2*n_pos[b];
  if (K <= 0){ if (t==0) phard[b*CHn+c] = 0.0; return; }
  const float* cn = conf_neg + (size_t)b*Pn;
  int p0=c*CHUNK, p1=min(Pn,p0+CHUNK);
  float s=0.0f;
  if (K >= Pn){
    for (int p=p0+t;p<p1;p+=256) s += cn[p];
  } else {
    unsigned tb = prefix[b];
    for (int p=p0+t;p<p1;p+=256){
      float v = cn[p];
      if (__float_as_uint(v) > tb) s += v;
    }
  }
  __shared__ float sr[256];
  sr[t]=s; __syncthreads();
  for (int st=128;st>0;st>>=1){ if(t<st) sr[t]+=sr[t+st]; __syncthreads(); }
  if (t==0){
    double add = (double)sr[0];
    if (c==0 && K < Pn) add += (double)krem_st[b] * (double)__uint_as_float(prefix[b]);
    phard[b*CHn+c] = add;
  }
}

// ---- final combine: sum all partial arrays in doubles ----
__global__ void final_kernel(const int* __restrict__ n_pos,
                             const float* __restrict__ pseg,
                             const float* __restrict__ ploc,
                             const float* __restrict__ pconf,
                             const double* __restrict__ phard,
                             float* __restrict__ out){
  int t = threadIdx.x;
  double seg_s=0.0, loc_s=0.0, conf_s=0.0, hard_s=0.0;
  for (int i=t;i<SEGB;i+=256)     seg_s  += (double)pseg[i];
  for (int i=t;i<Bn*WPB;i+=256)   loc_s  += (double)ploc[i];
  for (int i=t;i<Bn*WPB;i+=256)   conf_s += (double)pconf[i];
  for (int i=t;i<Bn*CHn;i+=256)   hard_s += phard[i];
  int tp_s = (t < Bn) ? n_pos[t] : 0;
  __shared__ double sd[256];
  __shared__ int    si_[256];
  si_[t]=tp_s;
  sd[t]=seg_s;  __syncthreads();
  for (int st=128;st>0;st>>=1){ if(t<st){ sd[t]+=sd[t+st]; si_[t]+=si_[t+st]; } __syncthreads(); }
  double seg_t = sd[0]; int tp = si_[0];
  __syncthreads();
  sd[t]=loc_s;  __syncthreads();
  for (int st=128;st>0;st>>=1){ if(t<st) sd[t]+=sd[t+st]; __syncthreads(); }
  double loc_t = sd[0];
  __syncthreads();
  sd[t]=conf_s+hard_s; __syncthreads();
  for (int st=128;st>0;st>>=1){ if(t<st) sd[t]+=sd[t+st]; __syncthreads(); }
  double conf_t = sd[0];
  if (t==0){
    float total = (float)tp;
    float conf_loss = (float)conf_t / total;
    float loc_loss  = (float)loc_t / total;
    float seg_loss  = -(float)seg_t;
    out[0] = conf_loss + loc_loss + seg_loss;
  }
}

extern "C" void kernel_launch(void* const* d_in, const int* in_sizes, int n_in,
                              void* d_out, int out_size, void* d_ws, size_t ws_size,
                              hipStream_t stream) {
  const float* odm_locs   = (const float*)d_in[0];
  const float* odm_scores = (const float*)d_in[1];
  const float* att        = (const float*)d_in[2];
  const float* boxes      = (const float*)d_in[3];
  const int*   labels     = (const int*)d_in[4];
  const float* ign        = (const float*)d_in[5];
  const float* priors     = (const float*)d_in[6];
  float* out = (float*)d_out;

  size_t np = (size_t)Bn * Pn;
  float* ov_prior  = (float*)d_ws;                 // B*P f32
  int*   objinfo   = (int*)(ov_prior + np);        // B*P i32 (bits0-7 obj, bit8 ignored)
  float* conf_neg  = (float*)(objinfo + np);       // B*P f32
  unsigned long long* key_obj = (unsigned long long*)(conf_neg + np); // B*O u64
  double* phard    = (double*)(key_obj + (size_t)Bn*On); // B*CHn f64
  int*    n_pos    = (int*)(phard + (size_t)Bn*CHn);     // B i32
  float*  pseg     = (float*)(n_pos + Bn);               // SEGB f32
  float*  ploc     = pseg + SEGB;                        // B*WPB f32
  float*  pconf    = ploc + (size_t)Bn*WPB;              // B*WPB f32
  int*    ppos     = (int*)(pconf + (size_t)Bn*WPB);     // B*WPB i32

  // radix-select scratch lives in the ov_prior region (dead after phaseD):
  unsigned* histB  = (unsigned*)ov_prior;
  unsigned* prefix = histB + 3*(size_t)Bn*4096;
  int*      krem   = (int*)(prefix + Bn);

  // only key_obj needs zeroing (atomicMax targets); partials are fully written
  hipMemsetAsync(key_obj, 0, (size_t)Bn*On*8, stream);

  int pblocks = (Pn + 255) / 256;
  seg_kernel  <<<SEGB, 256, 0, stream>>>(att, pseg);
  phaseA_kernel<<<dim3(pblocks, Bn), 256, 0, stream>>>(boxes, ign, priors, ov_prior, objinfo);
  phaseB_kernel<<<dim3(PCn, On/OC, Bn), 256, 0, stream>>>(boxes, priors, key_obj);
  phaseC_kernel<<<1, 64, 0, stream>>>(key_obj, ov_prior, objinfo);
  phaseD_kernel<<<dim3(DBLK, Bn), 256, 0, stream>>>(odm_locs, odm_scores, boxes, labels,
                                                    priors, ov_prior, objinfo,
                                                    conf_neg, ploc, pconf, ppos);
  npos_kernel<<<1, 64, 0, stream>>>(ppos, n_pos);
  // ov_prior is dead from here; reuse as radix scratch.
  hipMemsetAsync(histB, 0, 3*(size_t)Bn*4096*sizeof(unsigned), stream);
  histE_kernel<0><<<dim3(CHn, Bn), 256, 0, stream>>>(conf_neg, n_pos, prefix, histB);
  scanE_kernel<0><<<Bn, 256, 0, stream>>>(histB, n_pos, prefix, krem);
  histE_kernel<1><<<dim3(CHn, Bn), 256, 0, stream>>>(conf_neg, n_pos, prefix, histB + (size_t)Bn*4096);
  scanE_kernel<1><<<Bn, 256, 0, stream>>>(histB + (size_t)Bn*4096, n_pos, prefix, krem);
  histE_kernel<2><<<dim3(CHn, Bn), 256, 0, stream>>>(conf_neg, n_pos, prefix, histB + 2*(size_t)Bn*4096);
  scanE_kernel<2><<<Bn, 256, 0, stream>>>(histB + 2*(size_t)Bn*4096, n_pos, prefix, krem);
  finalE_kernel<<<dim3(CHn, Bn), 256, 0, stream>>>(conf_neg, n_pos, prefix, krem, phard);
  final_kernel<<<1, 256, 0, stream>>>(n_pos, pseg, ploc, pconf, phard, out);
}